// Round 1
// baseline (3677.740 us; speedup 1.0000x reference)
//
#include <hip/hip_runtime.h>

#define N_NODES 100000
#define N_EDGES 640000
#define D_IN 128
#define D_HID 256
#define D_OUT 64

// workspace layout (float offsets)
#define OFF_DEG   0
#define OFF_AGG1  102400                          // deg padded to 102400
#define OFF_H     (OFF_AGG1 + N_NODES * D_IN)     // 12,902,400
#define OFF_AGG2  (OFF_H + N_NODES * D_HID)       // 38,502,400

// ---------------- scatter (sum of src rows into dst rows) ----------------

__global__ __launch_bounds__(256) void k_scatter1(
    const float* __restrict__ x, const int* __restrict__ src,
    const int* __restrict__ dst, float* __restrict__ agg,
    float* __restrict__ deg)
{
    int idx = blockIdx.x * 256 + threadIdx.x;     // E*32 threads, 4 feats each
    int e = idx >> 5;
    int c = (idx & 31) << 2;
    int s = src[e], d = dst[e];
    float4 v = *(const float4*)(x + (size_t)s * D_IN + c);
    float* p = agg + (size_t)d * D_IN + c;
    atomicAdd(p + 0, v.x); atomicAdd(p + 1, v.y);
    atomicAdd(p + 2, v.z); atomicAdd(p + 3, v.w);
    if ((idx & 31) == 0) atomicAdd(deg + d, 1.0f);
}

__global__ __launch_bounds__(256) void k_scatter2(
    const float* __restrict__ h, const int* __restrict__ src,
    const int* __restrict__ dst, float* __restrict__ agg)
{
    int idx = blockIdx.x * 256 + threadIdx.x;     // E*64 threads, 4 feats each
    int e = idx >> 6;
    int c = (idx & 63) << 2;
    int s = src[e], d = dst[e];
    float4 v = *(const float4*)(h + (size_t)s * D_HID + c);
    float* p = agg + (size_t)d * D_HID + c;
    atomicAdd(p + 0, v.x); atomicAdd(p + 1, v.y);
    atomicAdd(p + 2, v.z); atomicAdd(p + 3, v.w);
}

__global__ __launch_bounds__(256) void k_recip(float* __restrict__ deg)
{
    int i = blockIdx.x * 256 + threadIdx.x;
    if (i < N_NODES) deg[i] = 1.0f / fmaxf(deg[i], 1.0f);
}

// ---------------- fused SAGE GEMM: out = act(agg*invdeg @ Wa.T + x @ Wr.T + b)

template<int KIN, int NOUT, bool RELU>
__global__ __launch_bounds__(256) void k_sage_gemm(
    const float* __restrict__ aggr,   // [N, KIN] summed messages
    const float* __restrict__ xin,    // [N, KIN] root features
    const float* __restrict__ invdeg, // [N]
    const float* __restrict__ w_agg,  // [NOUT, KIN]
    const float* __restrict__ w_root, // [NOUT, KIN]
    const float* __restrict__ bias,   // [NOUT]
    float* __restrict__ out)          // [N, NOUT]
{
    __shared__ float As[16][68];      // k-major, +4 pad (16B-aligned rows)
    __shared__ float Bs[16][68];

    const int tid = threadIdx.x;
    const int tx = tid & 15, ty = tid >> 4;
    const int row0 = blockIdx.x * 64;
    const int col0 = blockIdx.y * 64;
    const int lr = tid >> 2;          // 0..63: tile row (A) / tile col (B)
    const int ls = (tid & 3) << 2;    // 0,4,8,12: k segment

    const int arow = row0 + lr;
    const float id = (arow < N_NODES) ? invdeg[arow] : 0.0f;
    const int bcol = col0 + lr;       // always < NOUT (tiles exact)

    float acc[4][4] = {};

    for (int k0 = 0; k0 < 2 * KIN; k0 += 16) {
        // global loads (float4, segment never crosses the KIN boundary)
        int k = k0 + ls;
        float4 av = make_float4(0.f, 0.f, 0.f, 0.f);
        if (arow < N_NODES) {
            if (k < KIN) {
                av = *(const float4*)(aggr + (size_t)arow * KIN + k);
                av.x *= id; av.y *= id; av.z *= id; av.w *= id;
            } else {
                av = *(const float4*)(xin + (size_t)arow * KIN + (k - KIN));
            }
        }
        float4 bv;
        if (k < KIN) bv = *(const float4*)(w_agg + (size_t)bcol * KIN + k);
        else         bv = *(const float4*)(w_root + (size_t)bcol * KIN + (k - KIN));

        __syncthreads();
        As[ls + 0][lr] = av.x; As[ls + 1][lr] = av.y;
        As[ls + 2][lr] = av.z; As[ls + 3][lr] = av.w;
        Bs[ls + 0][lr] = bv.x; Bs[ls + 1][lr] = bv.y;
        Bs[ls + 2][lr] = bv.z; Bs[ls + 3][lr] = bv.w;
        __syncthreads();

        #pragma unroll
        for (int kk = 0; kk < 16; ++kk) {
            float4 a = *(const float4*)&As[kk][ty * 4];
            float4 b = *(const float4*)&Bs[kk][tx * 4];
            acc[0][0] += a.x * b.x; acc[0][1] += a.x * b.y;
            acc[0][2] += a.x * b.z; acc[0][3] += a.x * b.w;
            acc[1][0] += a.y * b.x; acc[1][1] += a.y * b.y;
            acc[1][2] += a.y * b.z; acc[1][3] += a.y * b.w;
            acc[2][0] += a.z * b.x; acc[2][1] += a.z * b.y;
            acc[2][2] += a.z * b.z; acc[2][3] += a.z * b.w;
            acc[3][0] += a.w * b.x; acc[3][1] += a.w * b.y;
            acc[3][2] += a.w * b.z; acc[3][3] += a.w * b.w;
        }
    }

    const int orow = row0 + ty * 4;
    const int ocol = col0 + tx * 4;
    #pragma unroll
    for (int i = 0; i < 4; ++i) {
        if (orow + i < N_NODES) {
            #pragma unroll
            for (int j = 0; j < 4; ++j) {
                float v = acc[i][j] + bias[ocol + j];
                if (RELU) v = fmaxf(v, 0.0f);
                out[(size_t)(orow + i) * NOUT + (ocol + j)] = v;
            }
        }
    }
}

// ---------------- log_softmax over 64 classes, one wave per row ----------

__global__ __launch_bounds__(256) void k_logsoftmax(float* __restrict__ out)
{
    int row = blockIdx.x * 4 + (threadIdx.x >> 6);
    int lane = threadIdx.x & 63;
    if (row >= N_NODES) return;
    float v = out[(size_t)row * 64 + lane];
    float m = v;
    #pragma unroll
    for (int o = 1; o < 64; o <<= 1) m = fmaxf(m, __shfl_xor(m, o));
    float s = expf(v - m);
    #pragma unroll
    for (int o = 1; o < 64; o <<= 1) s += __shfl_xor(s, o);
    out[(size_t)row * 64 + lane] = v - m - logf(s);
}

// ---------------- launch ----------------

extern "C" void kernel_launch(void* const* d_in, const int* in_sizes, int n_in,
                              void* d_out, int out_size, void* d_ws, size_t ws_size,
                              hipStream_t stream)
{
    const float* x   = (const float*)d_in[0];
    const int*   ei  = (const int*)d_in[1];
    const float* w1a = (const float*)d_in[2];
    const float* b1  = (const float*)d_in[3];
    const float* w1r = (const float*)d_in[4];
    const float* w2a = (const float*)d_in[5];
    const float* b2  = (const float*)d_in[6];
    const float* w2r = (const float*)d_in[7];
    float* out = (float*)d_out;
    float* ws  = (float*)d_ws;

    const int* src = ei;
    const int* dst = ei + N_EDGES;

    float* deg  = ws + OFF_DEG;
    float* agg1 = ws + OFF_AGG1;
    float* h    = ws + OFF_H;
    float* agg2 = ws + OFF_AGG2;

    hipMemsetAsync(deg, 0, (size_t)N_NODES * 4, stream);
    hipMemsetAsync(agg1, 0, (size_t)N_NODES * D_IN * 4, stream);
    hipMemsetAsync(agg2, 0, (size_t)N_NODES * D_HID * 4, stream);

    k_scatter1<<<(N_EDGES * 32) / 256, 256, 0, stream>>>(x, src, dst, agg1, deg);
    k_recip<<<(N_NODES + 255) / 256, 256, 0, stream>>>(deg);

    dim3 g1(1563, D_HID / 64);
    k_sage_gemm<D_IN, D_HID, true><<<g1, 256, 0, stream>>>(
        agg1, x, deg, w1a, w1r, b1, h);

    k_scatter2<<<(N_EDGES * 64) / 256, 256, 0, stream>>>(h, src, dst, agg2);

    dim3 g2(1563, 1);
    k_sage_gemm<D_HID, D_OUT, false><<<g2, 256, 0, stream>>>(
        agg2, h, deg, w2a, w2r, b2, out);

    k_logsoftmax<<<25000, 256, 0, stream>>>(out);
}

// Round 2
// 548.404 us; speedup vs baseline: 6.7063x; 6.7063x over previous
//
#include <hip/hip_runtime.h>

#define N_NODES 100000
#define N_EDGES 640000
#define D_IN 128
#define D_HID 256
#define D_OUT 64

#define NPAD 100352                  // N_NODES padded to 256
#define NB_SCAN 391                  // ceil(100000/256)

// workspace layout (4-byte word offsets)
#define OFF_CNT      0               // int [NPAD]
#define OFF_RSTART   (OFF_CNT + NPAD)        // int [NPAD]
#define OFF_CURSOR   (OFF_RSTART + NPAD)     // int [NPAD]
#define OFF_BSUMS    (OFF_CURSOR + NPAD)     // int [512]
#define OFF_CSRC     (OFF_BSUMS + 512)       // int [N_EDGES]
#define OFF_INVDEG   (OFF_CSRC + N_EDGES)    // float [NPAD]
#define OFF_AGG1     (OFF_INVDEG + NPAD)     // float [N, 128]
#define OFF_H        (OFF_AGG1 + N_NODES * D_IN)   // float [N, 256]
#define OFF_CAT2     (OFF_H + N_NODES * D_HID)     // float [N, 128]

// ---------------- CSR build ----------------

__global__ __launch_bounds__(256) void k_hist(
    const int* __restrict__ dst, int* __restrict__ cnt)
{
    int e = blockIdx.x * 256 + threadIdx.x;
    atomicAdd(&cnt[dst[e]], 1);
}

__global__ __launch_bounds__(256) void k_scan1(
    const int* __restrict__ cnt, int* __restrict__ bsums)
{
    __shared__ int s[256];
    int i = blockIdx.x * 256 + threadIdx.x;
    int v = (i < N_NODES) ? cnt[i] : 0;
    s[threadIdx.x] = v;
    __syncthreads();
    for (int o = 128; o > 0; o >>= 1) {
        if (threadIdx.x < o) s[threadIdx.x] += s[threadIdx.x + o];
        __syncthreads();
    }
    if (threadIdx.x == 0) bsums[blockIdx.x] = s[0];
}

__global__ __launch_bounds__(512) void k_scan2(int* __restrict__ bsums)
{
    __shared__ int s[512];
    int t = threadIdx.x;
    int v = (t < NB_SCAN) ? bsums[t] : 0;
    s[t] = v;
    __syncthreads();
    for (int o = 1; o < 512; o <<= 1) {
        int a = (t >= o) ? s[t - o] : 0;
        __syncthreads();
        s[t] += a;
        __syncthreads();
    }
    if (t < NB_SCAN) bsums[t] = s[t] - v;   // exclusive
}

__global__ __launch_bounds__(256) void k_scan3(
    const int* __restrict__ cnt, const int* __restrict__ bsums,
    int* __restrict__ row_start, int* __restrict__ cursor,
    float* __restrict__ invdeg)
{
    __shared__ int s[256];
    int i = blockIdx.x * 256 + threadIdx.x;
    int v = (i < N_NODES) ? cnt[i] : 0;
    s[threadIdx.x] = v;
    __syncthreads();
    for (int o = 1; o < 256; o <<= 1) {
        int a = (threadIdx.x >= o) ? s[threadIdx.x - o] : 0;
        __syncthreads();
        s[threadIdx.x] += a;
        __syncthreads();
    }
    if (i < N_NODES) {
        int excl = s[threadIdx.x] - v + bsums[blockIdx.x];
        row_start[i] = excl;
        cursor[i] = excl;
        invdeg[i] = 1.0f / fmaxf((float)v, 1.0f);
    }
}

__global__ __launch_bounds__(256) void k_fill(
    const int* __restrict__ src, const int* __restrict__ dst,
    int* __restrict__ cursor, int* __restrict__ csr_src)
{
    int e = blockIdx.x * 256 + threadIdx.x;
    int pos = atomicAdd(&cursor[dst[e]], 1);
    csr_src[pos] = src[e];
}

// ---------------- gather-sum of x rows (layer 1), one wave per node ------

__global__ __launch_bounds__(256) void k_gather1(
    const float* __restrict__ x, const int* __restrict__ row_start,
    const int* __restrict__ cnt, const int* __restrict__ csr_src,
    float* __restrict__ agg1)
{
    int node = blockIdx.x * 4 + (threadIdx.x >> 6);
    if (node >= N_NODES) return;
    int lane = threadIdx.x & 63;
    int beg = row_start[node], n = cnt[node];
    float2 acc = make_float2(0.f, 0.f);
    for (int j = 0; j < n; ++j) {
        int s = csr_src[beg + j];
        float2 v = *(const float2*)(x + (size_t)s * D_IN + lane * 2);
        acc.x += v.x; acc.y += v.y;
    }
    *(float2*)(agg1 + (size_t)node * D_IN + lane * 2) = acc;
}

// ---------------- fused SAGE GEMM layer 1 --------------------------------
// h = relu(agg1*invdeg @ w1a.T + x @ w1r.T + b1)

__global__ __launch_bounds__(256) void k_gemm1(
    const float* __restrict__ aggr, const float* __restrict__ xin,
    const float* __restrict__ invdeg, const float* __restrict__ w_agg,
    const float* __restrict__ w_root, const float* __restrict__ bias,
    float* __restrict__ out)
{
    __shared__ float As[16][68];
    __shared__ float Bs[16][68];

    const int tid = threadIdx.x;
    const int tx = tid & 15, ty = tid >> 4;
    const int row0 = blockIdx.x * 64;
    const int col0 = blockIdx.y * 64;
    const int lr = tid >> 2;
    const int ls = (tid & 3) << 2;

    const int arow = row0 + lr;
    const float id = (arow < N_NODES) ? invdeg[arow] : 0.0f;
    const int bcol = col0 + lr;

    float acc[4][4] = {};

    for (int k0 = 0; k0 < 2 * D_IN; k0 += 16) {
        int k = k0 + ls;
        float4 av = make_float4(0.f, 0.f, 0.f, 0.f);
        if (arow < N_NODES) {
            if (k < D_IN) {
                av = *(const float4*)(aggr + (size_t)arow * D_IN + k);
                av.x *= id; av.y *= id; av.z *= id; av.w *= id;
            } else {
                av = *(const float4*)(xin + (size_t)arow * D_IN + (k - D_IN));
            }
        }
        float4 bv;
        if (k < D_IN) bv = *(const float4*)(w_agg + (size_t)bcol * D_IN + k);
        else          bv = *(const float4*)(w_root + (size_t)bcol * D_IN + (k - D_IN));

        __syncthreads();
        As[ls + 0][lr] = av.x; As[ls + 1][lr] = av.y;
        As[ls + 2][lr] = av.z; As[ls + 3][lr] = av.w;
        Bs[ls + 0][lr] = bv.x; Bs[ls + 1][lr] = bv.y;
        Bs[ls + 2][lr] = bv.z; Bs[ls + 3][lr] = bv.w;
        __syncthreads();

        #pragma unroll
        for (int kk = 0; kk < 16; ++kk) {
            float4 a = *(const float4*)&As[kk][ty * 4];
            float4 b = *(const float4*)&Bs[kk][tx * 4];
            acc[0][0] += a.x * b.x; acc[0][1] += a.x * b.y;
            acc[0][2] += a.x * b.z; acc[0][3] += a.x * b.w;
            acc[1][0] += a.y * b.x; acc[1][1] += a.y * b.y;
            acc[1][2] += a.y * b.z; acc[1][3] += a.y * b.w;
            acc[2][0] += a.z * b.x; acc[2][1] += a.z * b.y;
            acc[2][2] += a.z * b.z; acc[2][3] += a.z * b.w;
            acc[3][0] += a.w * b.x; acc[3][1] += a.w * b.y;
            acc[3][2] += a.w * b.z; acc[3][3] += a.w * b.w;
        }
    }

    const int orow = row0 + ty * 4;
    const int ocol = col0 + tx * 4;
    #pragma unroll
    for (int i = 0; i < 4; ++i) {
        if (orow + i < N_NODES) {
            #pragma unroll
            for (int j = 0; j < 4; ++j) {
                float v = acc[i][j] + bias[ocol + j];
                out[(size_t)(orow + i) * D_HID + (ocol + j)] = fmaxf(v, 0.0f);
            }
        }
    }
}

// ---------------- layer-2 GEMM: cat2 = [h@w2r.T + b2 | h@w2a.T] ----------

__global__ __launch_bounds__(256) void k_gemm2(
    const float* __restrict__ h, const float* __restrict__ w2r,
    const float* __restrict__ w2a, const float* __restrict__ b2,
    float* __restrict__ cat2)
{
    __shared__ float As[16][68];
    __shared__ float Bs[16][68];

    const int tid = threadIdx.x;
    const int tx = tid & 15, ty = tid >> 4;
    const int row0 = blockIdx.x * 64;
    const int col0 = blockIdx.y * 64;   // 0 = root half, 64 = agg half
    const int lr = tid >> 2;
    const int ls = (tid & 3) << 2;

    const int arow = row0 + lr;
    const int bcol = col0 + lr;
    const float* wrow = (col0 == 0) ? (w2r + (size_t)bcol * D_HID)
                                    : (w2a + (size_t)(bcol - 64) * D_HID);

    float acc[4][4] = {};

    for (int k0 = 0; k0 < D_HID; k0 += 16) {
        int k = k0 + ls;
        float4 av = make_float4(0.f, 0.f, 0.f, 0.f);
        if (arow < N_NODES)
            av = *(const float4*)(h + (size_t)arow * D_HID + k);
        float4 bv = *(const float4*)(wrow + k);

        __syncthreads();
        As[ls + 0][lr] = av.x; As[ls + 1][lr] = av.y;
        As[ls + 2][lr] = av.z; As[ls + 3][lr] = av.w;
        Bs[ls + 0][lr] = bv.x; Bs[ls + 1][lr] = bv.y;
        Bs[ls + 2][lr] = bv.z; Bs[ls + 3][lr] = bv.w;
        __syncthreads();

        #pragma unroll
        for (int kk = 0; kk < 16; ++kk) {
            float4 a = *(const float4*)&As[kk][ty * 4];
            float4 b = *(const float4*)&Bs[kk][tx * 4];
            acc[0][0] += a.x * b.x; acc[0][1] += a.x * b.y;
            acc[0][2] += a.x * b.z; acc[0][3] += a.x * b.w;
            acc[1][0] += a.y * b.x; acc[1][1] += a.y * b.y;
            acc[1][2] += a.y * b.z; acc[1][3] += a.y * b.w;
            acc[2][0] += a.z * b.x; acc[2][1] += a.z * b.y;
            acc[2][2] += a.z * b.z; acc[2][3] += a.z * b.w;
            acc[3][0] += a.w * b.x; acc[3][1] += a.w * b.y;
            acc[3][2] += a.w * b.z; acc[3][3] += a.w * b.w;
        }
    }

    const int orow = row0 + ty * 4;
    const int ocol = col0 + tx * 4;
    #pragma unroll
    for (int i = 0; i < 4; ++i) {
        if (orow + i < N_NODES) {
            #pragma unroll
            for (int j = 0; j < 4; ++j) {
                float v = acc[i][j];
                if (col0 == 0) v += b2[ocol + j];
                cat2[(size_t)(orow + i) * 128 + (ocol + j)] = v;
            }
        }
    }
}

// -------- final: gather-mean z2 + root + log_softmax, one wave per node --

__global__ __launch_bounds__(256) void k_final(
    const float* __restrict__ cat2, const int* __restrict__ row_start,
    const int* __restrict__ cnt, const float* __restrict__ invdeg,
    const int* __restrict__ csr_src, float* __restrict__ out)
{
    int node = blockIdx.x * 4 + (threadIdx.x >> 6);
    if (node >= N_NODES) return;
    int lane = threadIdx.x & 63;
    int beg = row_start[node], n = cnt[node];
    float acc = 0.0f;
    for (int j = 0; j < n; ++j) {
        int s = csr_src[beg + j];
        acc += cat2[(size_t)s * 128 + 64 + lane];
    }
    float v = acc * invdeg[node] + cat2[(size_t)node * 128 + lane];
    float m = v;
    #pragma unroll
    for (int o = 1; o < 64; o <<= 1) m = fmaxf(m, __shfl_xor(m, o));
    float e = expf(v - m);
    float s = e;
    #pragma unroll
    for (int o = 1; o < 64; o <<= 1) s += __shfl_xor(s, o);
    out[(size_t)node * 64 + lane] = v - m - logf(s);
}

// ---------------- launch ----------------

extern "C" void kernel_launch(void* const* d_in, const int* in_sizes, int n_in,
                              void* d_out, int out_size, void* d_ws, size_t ws_size,
                              hipStream_t stream)
{
    const float* x   = (const float*)d_in[0];
    const int*   ei  = (const int*)d_in[1];
    const float* w1a = (const float*)d_in[2];
    const float* b1  = (const float*)d_in[3];
    const float* w1r = (const float*)d_in[4];
    const float* w2a = (const float*)d_in[5];
    const float* b2  = (const float*)d_in[6];
    const float* w2r = (const float*)d_in[7];
    float* out = (float*)d_out;

    int*   wsi = (int*)d_ws;
    float* wsf = (float*)d_ws;

    const int* src = ei;
    const int* dst = ei + N_EDGES;

    int*   cnt       = wsi + OFF_CNT;
    int*   row_start = wsi + OFF_RSTART;
    int*   cursor    = wsi + OFF_CURSOR;
    int*   bsums     = wsi + OFF_BSUMS;
    int*   csr_src   = wsi + OFF_CSRC;
    float* invdeg    = wsf + OFF_INVDEG;
    float* agg1      = wsf + OFF_AGG1;
    float* h         = wsf + OFF_H;
    float* cat2      = wsf + OFF_CAT2;

    hipMemsetAsync(cnt, 0, (size_t)NPAD * 4, stream);

    k_hist<<<N_EDGES / 256, 256, 0, stream>>>(dst, cnt);
    k_scan1<<<NB_SCAN, 256, 0, stream>>>(cnt, bsums);
    k_scan2<<<1, 512, 0, stream>>>(bsums);
    k_scan3<<<NB_SCAN, 256, 0, stream>>>(cnt, bsums, row_start, cursor, invdeg);
    k_fill<<<N_EDGES / 256, 256, 0, stream>>>(src, dst, cursor, csr_src);

    k_gather1<<<(N_NODES + 3) / 4, 256, 0, stream>>>(x, row_start, cnt, csr_src, agg1);

    dim3 g1((N_NODES + 63) / 64, D_HID / 64);
    k_gemm1<<<g1, 256, 0, stream>>>(agg1, x, invdeg, w1a, w1r, b1, h);

    dim3 g2((N_NODES + 63) / 64, 2);
    k_gemm2<<<g2, 256, 0, stream>>>(h, w2r, w2a, b2, cat2);

    k_final<<<(N_NODES + 3) / 4, 256, 0, stream>>>(cat2, row_start, cnt, invdeg, csr_src, out);
}

// Round 3
// 294.757 us; speedup vs baseline: 12.4772x; 1.8605x over previous
//
#include <hip/hip_runtime.h>

#define N_NODES 100000
#define N_EDGES 640000
#define D_IN 128
#define D_HID 256
#define D_OUT 64

#define NPAD 100352                  // N padded to 256 (for scan)
#define NROWPAD 100096               // N padded to 128 (GEMM tiles, no guards)
#define NB_SCAN 391                  // ceil(100000/256)

// ---------------- workspace layout (byte offsets, all 16B-aligned) -------
#define OB_CNT      0u
#define OB_RSTART   401408u
#define OB_CURSOR   802816u
#define OB_BSUMS    1204224u
#define OB_CSRC     1206272u
#define OB_INVDEG   3766272u
#define OB_XB       4167680u                    // bf16 [NROWPAD][128]
#define OB_MEANB    29792256u                   // bf16 [NROWPAD][128]
#define OB_HB       55416832u                   // bf16 [NROWPAD][256]
#define OB_CAT2     106665984u                  // f32  [NROWPAD][128]
#define OB_WCAT1    157915136u                  // bf16 [256][256]
#define OB_WCAT2    158046208u                  // bf16 [128][256]

typedef __attribute__((ext_vector_type(8))) short bf16x8;
typedef __attribute__((ext_vector_type(4))) float f32x4;

__device__ __forceinline__ ushort f2bf(float f) {
    uint u = __float_as_uint(f);
    u += 0x7FFFu + ((u >> 16) & 1u);          // round-to-nearest-even
    return (ushort)(u >> 16);
}

// ---------------- CSR build ----------------

__global__ __launch_bounds__(256) void k_hist(
    const int* __restrict__ dst, int* __restrict__ cnt)
{
    int e = blockIdx.x * 256 + threadIdx.x;
    atomicAdd(&cnt[dst[e]], 1);
}

__global__ __launch_bounds__(256) void k_scan1(
    const int* __restrict__ cnt, int* __restrict__ bsums)
{
    __shared__ int s[256];
    int i = blockIdx.x * 256 + threadIdx.x;
    int v = (i < N_NODES) ? cnt[i] : 0;
    s[threadIdx.x] = v;
    __syncthreads();
    for (int o = 128; o > 0; o >>= 1) {
        if (threadIdx.x < o) s[threadIdx.x] += s[threadIdx.x + o];
        __syncthreads();
    }
    if (threadIdx.x == 0) bsums[blockIdx.x] = s[0];
}

__global__ __launch_bounds__(512) void k_scan2(int* __restrict__ bsums)
{
    __shared__ int s[512];
    int t = threadIdx.x;
    int v = (t < NB_SCAN) ? bsums[t] : 0;
    s[t] = v;
    __syncthreads();
    for (int o = 1; o < 512; o <<= 1) {
        int a = (t >= o) ? s[t - o] : 0;
        __syncthreads();
        s[t] += a;
        __syncthreads();
    }
    if (t < NB_SCAN) bsums[t] = s[t] - v;   // exclusive
}

__global__ __launch_bounds__(256) void k_scan3(
    const int* __restrict__ cnt, const int* __restrict__ bsums,
    int* __restrict__ row_start, int* __restrict__ cursor,
    float* __restrict__ invdeg)
{
    __shared__ int s[256];
    int i = blockIdx.x * 256 + threadIdx.x;
    int v = (i < N_NODES) ? cnt[i] : 0;
    s[threadIdx.x] = v;
    __syncthreads();
    for (int o = 1; o < 256; o <<= 1) {
        int a = (threadIdx.x >= o) ? s[threadIdx.x - o] : 0;
        __syncthreads();
        s[threadIdx.x] += a;
        __syncthreads();
    }
    if (i < N_NODES) {
        int excl = s[threadIdx.x] - v + bsums[blockIdx.x];
        row_start[i] = excl;
        cursor[i] = excl;
        invdeg[i] = 1.0f / fmaxf((float)v, 1.0f);
    }
}

__global__ __launch_bounds__(256) void k_fill(
    const int* __restrict__ src, const int* __restrict__ dst,
    int* __restrict__ cursor, int* __restrict__ csr_src)
{
    int e = blockIdx.x * 256 + threadIdx.x;
    int pos = atomicAdd(&cursor[dst[e]], 1);
    csr_src[pos] = src[e];
}

// ---------------- bf16 prep ----------------

__global__ __launch_bounds__(256) void k_cast_x(
    const float* __restrict__ x, ushort* __restrict__ xb)
{
    size_t i = (size_t)(blockIdx.x * 256 + threadIdx.x) * 4;   // 4 elems/thread
    float4 v = *(const float4*)(x + i);
    ushort4 o;
    o.x = f2bf(v.x); o.y = f2bf(v.y); o.z = f2bf(v.z); o.w = f2bf(v.w);
    *(ushort4*)(xb + i) = o;
}

__global__ __launch_bounds__(256) void k_prep_w(
    const float* __restrict__ w1a, const float* __restrict__ w1r,
    const float* __restrict__ w2r, const float* __restrict__ w2a,
    ushort* __restrict__ wcat1, ushort* __restrict__ wcat2)
{
    int i = blockIdx.x * 256 + threadIdx.x;
    if (i < 65536) {                 // wcat1 [256][256] = [w1a | w1r]
        int n = i >> 8, k = i & 255;
        float v = (k < 128) ? w1a[n * 128 + k] : w1r[n * 128 + (k - 128)];
        wcat1[i] = f2bf(v);
    } else if (i < 98304) {          // wcat2 [128][256] = [w2r ; w2a]
        int j = i - 65536;
        int n = j >> 8, k = j & 255;
        float v = (n < 64) ? w2r[n * 256 + k] : w2a[(n - 64) * 256 + k];
        wcat2[j] = f2bf(v);
    }
}

// ---------------- gather-mean of xb rows, one wave per node --------------

__global__ __launch_bounds__(256) void k_gather(
    const ushort* __restrict__ xb, const int* __restrict__ row_start,
    const int* __restrict__ cnt, const int* __restrict__ csr_src,
    const float* __restrict__ invdeg, ushort* __restrict__ meanb)
{
    int node = blockIdx.x * 4 + (threadIdx.x >> 6);
    if (node >= N_NODES) return;
    int lane = threadIdx.x & 63;
    int beg = row_start[node], n = cnt[node];
    float a0 = 0.f, a1 = 0.f;
    for (int j = 0; j < n; ++j) {
        int s = csr_src[beg + j];
        uint v = *(const uint*)(xb + (size_t)s * D_IN + lane * 2);
        a0 += __uint_as_float(v << 16);
        a1 += __uint_as_float(v & 0xFFFF0000u);
    }
    float id = invdeg[node];
    uint o = (uint)f2bf(a0 * id) | ((uint)f2bf(a1 * id) << 16);
    *(uint*)(meanb + (size_t)node * D_IN + lane * 2) = o;
}

// ---------------- MFMA GEMM: OUT[M,NOUT] = [A0|A1] @ Bcat.T (+bias, act) --
// 128x128 tile, 4 waves (2x2), BK=64, K=256.  LDS XOR-swizzled (rule #21):
// pre-swizzled global source + linear global_load_lds dest + swizzled read.

template<int AW, int NOUT, bool RELU, bool OUT_BF16, bool BIAS64>
__global__ __launch_bounds__(256, 2) void k_gemm(
    const ushort* __restrict__ A0, const ushort* __restrict__ A1,
    const ushort* __restrict__ B,     // [NOUT][256] bf16
    const float* __restrict__ bias,
    void* __restrict__ outv)
{
    __shared__ ushort lds[2 * 128 * 64];   // A: [0,16KB), B: [16KB,32KB)

    const int tid = threadIdx.x;
    const int lane = tid & 63;
    const int w = tid >> 6;
    const int wm = w >> 1, wn = w & 1;
    const int row0 = blockIdx.x * 128;
    const int col0 = blockIdx.y * 128;

    f32x4 acc[4][4] = {};   // [mi][ni]

    for (int kt = 0; kt < 4; ++kt) {
        const int k0 = kt * 64;
        const ushort* asrc;
        int kofs;
        if (AW == 256) { asrc = A0; kofs = k0; }
        else { asrc = (k0 < 128) ? A0 : A1; kofs = k0 & 127; }

        // stage A tile [128 rows][64 bf16], 4 issues x 4KB
        #pragma unroll
        for (int i = 0; i < 4; ++i) {
            int elem = i * 256 + tid;         // 16B-chunk index
            int r = elem >> 3;                // row 0..127
            int c8 = (elem & 7) ^ (r & 7);    // swizzled source chunk
            const ushort* g = asrc + (size_t)(row0 + r) * AW + kofs + c8 * 8;
            __builtin_amdgcn_global_load_lds(
                (const __attribute__((address_space(1))) void*)g,
                (__attribute__((address_space(3))) void*)&lds[i * 2048 + w * 512],
                16, 0, 0);
        }
        // stage B tile
        #pragma unroll
        for (int i = 0; i < 4; ++i) {
            int elem = i * 256 + tid;
            int r = elem >> 3;
            int c8 = (elem & 7) ^ (r & 7);
            const ushort* g = B + (size_t)(col0 + r) * 256 + k0 + c8 * 8;
            __builtin_amdgcn_global_load_lds(
                (const __attribute__((address_space(1))) void*)g,
                (__attribute__((address_space(3))) void*)&lds[8192 + i * 2048 + w * 512],
                16, 0, 0);
        }
        asm volatile("s_waitcnt vmcnt(0)" ::: "memory");
        __syncthreads();

        #pragma unroll
        for (int ks = 0; ks < 2; ++ks) {
            bf16x8 af[4], bfr[4];
            #pragma unroll
            for (int mi = 0; mi < 4; ++mi) {
                int r = wm * 64 + mi * 16 + (lane & 15);
                int c8 = ks * 4 + (lane >> 4);
                int byteoff = r * 128 + ((c8 ^ (r & 7)) * 16);
                af[mi] = *(const bf16x8*)((const char*)lds + byteoff);
            }
            #pragma unroll
            for (int ni = 0; ni < 4; ++ni) {
                int r = wn * 64 + ni * 16 + (lane & 15);
                int c8 = ks * 4 + (lane >> 4);
                int byteoff = 16384 + r * 128 + ((c8 ^ (r & 7)) * 16);
                bfr[ni] = *(const bf16x8*)((const char*)lds + byteoff);
            }
            #pragma unroll
            for (int mi = 0; mi < 4; ++mi)
                #pragma unroll
                for (int ni = 0; ni < 4; ++ni)
                    acc[mi][ni] = __builtin_amdgcn_mfma_f32_16x16x32_bf16(
                        af[mi], bfr[ni], acc[mi][ni], 0, 0, 0);
        }
        __syncthreads();
    }

    // epilogue: C/D map col=lane&15, row=(lane>>4)*4+reg
    const int orow_base = row0 + wm * 64;
    const int ocol_base = col0 + wn * 64;
    #pragma unroll
    for (int mi = 0; mi < 4; ++mi) {
        #pragma unroll
        for (int ni = 0; ni < 4; ++ni) {
            int ocol = ocol_base + ni * 16 + (lane & 15);
            float bv;
            if (BIAS64) bv = (ocol < 64) ? bias[ocol] : 0.0f;
            else        bv = bias[ocol];
            #pragma unroll
            for (int r = 0; r < 4; ++r) {
                int orow = orow_base + mi * 16 + (lane >> 4) * 4 + r;
                float v = acc[mi][ni][r] + bv;
                if (RELU) v = fmaxf(v, 0.0f);
                if (OUT_BF16)
                    ((ushort*)outv)[(size_t)orow * NOUT + ocol] = f2bf(v);
                else
                    ((float*)outv)[(size_t)orow * NOUT + ocol] = v;
            }
        }
    }
}

// -------- final: gather-mean agg half of cat2 + root + log_softmax -------

__global__ __launch_bounds__(256) void k_final(
    const float* __restrict__ cat2, const int* __restrict__ row_start,
    const int* __restrict__ cnt, const float* __restrict__ invdeg,
    const int* __restrict__ csr_src, float* __restrict__ out)
{
    int node = blockIdx.x * 4 + (threadIdx.x >> 6);
    if (node >= N_NODES) return;
    int lane = threadIdx.x & 63;
    int beg = row_start[node], n = cnt[node];
    float acc = 0.0f;
    for (int j = 0; j < n; ++j) {
        int s = csr_src[beg + j];
        acc += cat2[(size_t)s * 128 + 64 + lane];
    }
    float v = acc * invdeg[node] + cat2[(size_t)node * 128 + lane];
    float m = v;
    #pragma unroll
    for (int o = 1; o < 64; o <<= 1) m = fmaxf(m, __shfl_xor(m, o));
    float e = expf(v - m);
    float s = e;
    #pragma unroll
    for (int o = 1; o < 64; o <<= 1) s += __shfl_xor(s, o);
    out[(size_t)node * 64 + lane] = v - m - logf(s);
}

// ---------------- launch ----------------

extern "C" void kernel_launch(void* const* d_in, const int* in_sizes, int n_in,
                              void* d_out, int out_size, void* d_ws, size_t ws_size,
                              hipStream_t stream)
{
    const float* x   = (const float*)d_in[0];
    const int*   ei  = (const int*)d_in[1];
    const float* w1a = (const float*)d_in[2];
    const float* b1  = (const float*)d_in[3];
    const float* w1r = (const float*)d_in[4];
    const float* w2a = (const float*)d_in[5];
    const float* b2  = (const float*)d_in[6];
    const float* w2r = (const float*)d_in[7];
    float* out = (float*)d_out;

    char* ws = (char*)d_ws;
    const int* src = ei;
    const int* dst = ei + N_EDGES;

    int*    cnt       = (int*)(ws + OB_CNT);
    int*    row_start = (int*)(ws + OB_RSTART);
    int*    cursor    = (int*)(ws + OB_CURSOR);
    int*    bsums     = (int*)(ws + OB_BSUMS);
    int*    csr_src   = (int*)(ws + OB_CSRC);
    float*  invdeg    = (float*)(ws + OB_INVDEG);
    ushort* xb        = (ushort*)(ws + OB_XB);
    ushort* meanb     = (ushort*)(ws + OB_MEANB);
    ushort* hb        = (ushort*)(ws + OB_HB);
    float*  cat2      = (float*)(ws + OB_CAT2);
    ushort* wcat1     = (ushort*)(ws + OB_WCAT1);
    ushort* wcat2     = (ushort*)(ws + OB_WCAT2);

    hipMemsetAsync(cnt, 0, (size_t)NPAD * 4, stream);

    k_hist<<<N_EDGES / 256, 256, 0, stream>>>(dst, cnt);
    k_scan1<<<NB_SCAN, 256, 0, stream>>>(cnt, bsums);
    k_scan2<<<1, 512, 0, stream>>>(bsums);
    k_scan3<<<NB_SCAN, 256, 0, stream>>>(cnt, bsums, row_start, cursor, invdeg);
    k_fill<<<N_EDGES / 256, 256, 0, stream>>>(src, dst, cursor, csr_src);

    k_cast_x<<<12500, 256, 0, stream>>>(x, xb);
    k_prep_w<<<384, 256, 0, stream>>>(w1a, w1r, w2r, w2a, wcat1, wcat2);

    k_gather<<<(N_NODES + 3) / 4, 256, 0, stream>>>(
        xb, row_start, cnt, csr_src, invdeg, meanb);

    dim3 g1(NROWPAD / 128, 2);
    k_gemm<128, 256, true, true, false><<<g1, 256, 0, stream>>>(
        meanb, xb, wcat1, b1, (void*)hb);

    dim3 g2(NROWPAD / 128, 1);
    k_gemm<256, 128, false, false, true><<<g2, 256, 0, stream>>>(
        hb, hb, wcat2, b2, (void*)cat2);

    k_final<<<(N_NODES + 3) / 4, 256, 0, stream>>>(
        cat2, row_start, cnt, invdeg, csr_src, out);
}

// Round 4
// 239.255 us; speedup vs baseline: 15.3716x; 1.2320x over previous
//
#include <hip/hip_runtime.h>

#define N_NODES 100000
#define N_EDGES 640000
#define D_IN 128
#define D_HID 256
#define D_OUT 64

#define NPAD 100352                  // N padded to 256 (for scan)
#define NROWPAD 100096               // N padded to 128 (GEMM tiles, no guards)
#define NB_SCAN 391                  // ceil(100000/256)

// ---------------- workspace layout (byte offsets, all 16B-aligned) -------
#define OB_CNT      0u
#define OB_RSTART   401408u
#define OB_CURSOR   802816u
#define OB_BSUMS    1204224u
#define OB_CSRC     1206272u
#define OB_INVDEG   3766272u
#define OB_XB       4167680u                    // bf16 [NROWPAD][128]
#define OB_MEANB    29792256u                   // bf16 [NROWPAD][128]
#define OB_HB       55416832u                   // bf16 [NROWPAD][256]
#define OB_ZR       106665984u                  // f32  [NROWPAD][64] root+bias
#define OB_ZA       132290560u                  // bf16 [NROWPAD][64] agg half
#define OB_WCAT1    145102848u                  // bf16 [256][256]
#define OB_WCAT2    145233920u                  // bf16 [128][256]

typedef __attribute__((ext_vector_type(8))) short bf16x8;
typedef __attribute__((ext_vector_type(4))) float f32x4;

__device__ __forceinline__ ushort f2bf(float f) {
    uint u = __float_as_uint(f);
    u += 0x7FFFu + ((u >> 16) & 1u);          // round-to-nearest-even
    return (ushort)(u >> 16);
}
__device__ __forceinline__ float bflo(uint v) { return __uint_as_float(v << 16); }
__device__ __forceinline__ float bfhi(uint v) { return __uint_as_float(v & 0xFFFF0000u); }
__device__ __forceinline__ float bf1(ushort u) { return __uint_as_float((uint)u << 16); }

// ---------------- CSR build ----------------

__global__ __launch_bounds__(256) void k_hist(
    const int* __restrict__ dst, int* __restrict__ cnt)
{
    int e = blockIdx.x * 256 + threadIdx.x;
    atomicAdd(&cnt[dst[e]], 1);
}

__global__ __launch_bounds__(256) void k_scan1(
    const int* __restrict__ cnt, int* __restrict__ bsums)
{
    __shared__ int s[256];
    int i = blockIdx.x * 256 + threadIdx.x;
    int v = (i < N_NODES) ? cnt[i] : 0;
    s[threadIdx.x] = v;
    __syncthreads();
    for (int o = 128; o > 0; o >>= 1) {
        if (threadIdx.x < o) s[threadIdx.x] += s[threadIdx.x + o];
        __syncthreads();
    }
    if (threadIdx.x == 0) bsums[blockIdx.x] = s[0];
}

__global__ __launch_bounds__(512) void k_scan2(int* __restrict__ bsums)
{
    __shared__ int s[512];
    int t = threadIdx.x;
    int v = (t < NB_SCAN) ? bsums[t] : 0;
    s[t] = v;
    __syncthreads();
    for (int o = 1; o < 512; o <<= 1) {
        int a = (t >= o) ? s[t - o] : 0;
        __syncthreads();
        s[t] += a;
        __syncthreads();
    }
    if (t < NB_SCAN) bsums[t] = s[t] - v;   // exclusive
}

__global__ __launch_bounds__(256) void k_scan3(
    const int* __restrict__ cnt, const int* __restrict__ bsums,
    int* __restrict__ row_start, int* __restrict__ cursor,
    float* __restrict__ invdeg)
{
    __shared__ int s[256];
    int i = blockIdx.x * 256 + threadIdx.x;
    int v = (i < N_NODES) ? cnt[i] : 0;
    s[threadIdx.x] = v;
    __syncthreads();
    for (int o = 1; o < 256; o <<= 1) {
        int a = (threadIdx.x >= o) ? s[threadIdx.x - o] : 0;
        __syncthreads();
        s[threadIdx.x] += a;
        __syncthreads();
    }
    if (i < N_NODES) {
        int excl = s[threadIdx.x] - v + bsums[blockIdx.x];
        row_start[i] = excl;
        cursor[i] = excl;
        invdeg[i] = 1.0f / fmaxf((float)v, 1.0f);
    }
}

__global__ __launch_bounds__(256) void k_fill(
    const int* __restrict__ src, const int* __restrict__ dst,
    int* __restrict__ cursor, int* __restrict__ csr_src)
{
    int e = blockIdx.x * 256 + threadIdx.x;
    int pos = atomicAdd(&cursor[dst[e]], 1);
    csr_src[pos] = src[e];
}

// ---------------- bf16 prep ----------------

__global__ __launch_bounds__(256) void k_cast_x(
    const float* __restrict__ x, ushort* __restrict__ xb)
{
    size_t i = (size_t)(blockIdx.x * 256 + threadIdx.x) * 4;   // 4 elems/thread
    float4 v = *(const float4*)(x + i);
    ushort4 o;
    o.x = f2bf(v.x); o.y = f2bf(v.y); o.z = f2bf(v.z); o.w = f2bf(v.w);
    *(ushort4*)(xb + i) = o;
}

__global__ __launch_bounds__(256) void k_prep_w(
    const float* __restrict__ w1a, const float* __restrict__ w1r,
    const float* __restrict__ w2r, const float* __restrict__ w2a,
    ushort* __restrict__ wcat1, ushort* __restrict__ wcat2)
{
    int i = blockIdx.x * 256 + threadIdx.x;
    if (i < 65536) {                 // wcat1 [256][256] = [w1a | w1r]
        int n = i >> 8, k = i & 255;
        float v = (k < 128) ? w1a[n * 128 + k] : w1r[n * 128 + (k - 128)];
        wcat1[i] = f2bf(v);
    } else if (i < 98304) {          // wcat2 [128][256] = [w2r ; w2a]
        int j = i - 65536;
        int n = j >> 8, k = j & 255;
        float v = (n < 64) ? w2r[n * 256 + k] : w2a[(n - 64) * 256 + k];
        wcat2[j] = f2bf(v);
    }
}

// ---------------- gather-mean of xb rows, one wave per node --------------
// unrolled x4: four independent 256B row loads in flight

__global__ __launch_bounds__(256) void k_gather(
    const ushort* __restrict__ xb, const int* __restrict__ row_start,
    const int* __restrict__ cnt, const int* __restrict__ csr_src,
    const float* __restrict__ invdeg, ushort* __restrict__ meanb)
{
    int node = blockIdx.x * 4 + (threadIdx.x >> 6);
    if (node >= N_NODES) return;
    int lane = threadIdx.x & 63;
    int n = cnt[node];
    const int* cs = csr_src + row_start[node];
    float a0 = 0.f, a1 = 0.f;
    int j = 0;
    for (; j + 4 <= n; j += 4) {
        int4 s4 = *(const int4*)(cs + j);
        uint v0 = *(const uint*)(xb + (size_t)s4.x * D_IN + lane * 2);
        uint v1 = *(const uint*)(xb + (size_t)s4.y * D_IN + lane * 2);
        uint v2 = *(const uint*)(xb + (size_t)s4.z * D_IN + lane * 2);
        uint v3 = *(const uint*)(xb + (size_t)s4.w * D_IN + lane * 2);
        a0 += bflo(v0) + bflo(v1) + bflo(v2) + bflo(v3);
        a1 += bfhi(v0) + bfhi(v1) + bfhi(v2) + bfhi(v3);
    }
    for (; j < n; ++j) {
        int s = cs[j];
        uint v = *(const uint*)(xb + (size_t)s * D_IN + lane * 2);
        a0 += bflo(v); a1 += bfhi(v);
    }
    float id = invdeg[node];
    uint o = (uint)f2bf(a0 * id) | ((uint)f2bf(a1 * id) << 16);
    *(uint*)(meanb + (size_t)node * D_IN + lane * 2) = o;
}

// ---------------- MFMA GEMM: OUT[M,*] = [A0|A1] @ Bcat.T ------------------
// 128x128 tile, 4 waves (2x2), BK=64, K=256.  LDS XOR-swizzled (rule #21):
// pre-swizzled global source + linear global_load_lds dest + swizzled read.
// MODE 0: out0 = bf16 [M][256] relu(v + bias)        (layer 1)
// MODE 1: out0 = f32 [M][64] v+bias (cols 0-63), out1 = bf16 [M][64] (cols 64-127)

template<int AW, int MODE>
__global__ __launch_bounds__(256, 2) void k_gemm(
    const ushort* __restrict__ A0, const ushort* __restrict__ A1,
    const ushort* __restrict__ B,     // [*][256] bf16
    const float* __restrict__ bias,
    void* __restrict__ out0, void* __restrict__ out1)
{
    __shared__ ushort lds[2 * 128 * 64];   // A: [0,16KB), B: [16KB,32KB)

    const int tid = threadIdx.x;
    const int lane = tid & 63;
    const int w = tid >> 6;
    const int wm = w >> 1, wn = w & 1;
    const int row0 = blockIdx.x * 128;
    const int col0 = blockIdx.y * 128;

    f32x4 acc[4][4] = {};   // [mi][ni]

    for (int kt = 0; kt < 4; ++kt) {
        const int k0 = kt * 64;
        const ushort* asrc;
        int kofs;
        if (AW == 256) { asrc = A0; kofs = k0; }
        else { asrc = (k0 < 128) ? A0 : A1; kofs = k0 & 127; }

        // stage A tile [128 rows][64 bf16], 4 issues x 4KB
        #pragma unroll
        for (int i = 0; i < 4; ++i) {
            int elem = i * 256 + tid;         // 16B-chunk index
            int r = elem >> 3;                // row 0..127
            int c8 = (elem & 7) ^ (r & 7);    // swizzled source chunk
            const ushort* g = asrc + (size_t)(row0 + r) * AW + kofs + c8 * 8;
            __builtin_amdgcn_global_load_lds(
                (const __attribute__((address_space(1))) void*)g,
                (__attribute__((address_space(3))) void*)&lds[i * 2048 + w * 512],
                16, 0, 0);
        }
        // stage B tile
        #pragma unroll
        for (int i = 0; i < 4; ++i) {
            int elem = i * 256 + tid;
            int r = elem >> 3;
            int c8 = (elem & 7) ^ (r & 7);
            const ushort* g = B + (size_t)(col0 + r) * 256 + k0 + c8 * 8;
            __builtin_amdgcn_global_load_lds(
                (const __attribute__((address_space(1))) void*)g,
                (__attribute__((address_space(3))) void*)&lds[8192 + i * 2048 + w * 512],
                16, 0, 0);
        }
        asm volatile("s_waitcnt vmcnt(0)" ::: "memory");
        __syncthreads();

        #pragma unroll
        for (int ks = 0; ks < 2; ++ks) {
            bf16x8 af[4], bfr[4];
            #pragma unroll
            for (int mi = 0; mi < 4; ++mi) {
                int r = wm * 64 + mi * 16 + (lane & 15);
                int c8 = ks * 4 + (lane >> 4);
                int byteoff = r * 128 + ((c8 ^ (r & 7)) * 16);
                af[mi] = *(const bf16x8*)((const char*)lds + byteoff);
            }
            #pragma unroll
            for (int ni = 0; ni < 4; ++ni) {
                int r = wn * 64 + ni * 16 + (lane & 15);
                int c8 = ks * 4 + (lane >> 4);
                int byteoff = 16384 + r * 128 + ((c8 ^ (r & 7)) * 16);
                bfr[ni] = *(const bf16x8*)((const char*)lds + byteoff);
            }
            #pragma unroll
            for (int mi = 0; mi < 4; ++mi)
                #pragma unroll
                for (int ni = 0; ni < 4; ++ni)
                    acc[mi][ni] = __builtin_amdgcn_mfma_f32_16x16x32_bf16(
                        af[mi], bfr[ni], acc[mi][ni], 0, 0, 0);
        }
        __syncthreads();
    }

    // epilogue: C/D map col=lane&15, row=(lane>>4)*4+reg
    const int orow_base = row0 + wm * 64;
    const int ocol_base = col0 + wn * 64;
    #pragma unroll
    for (int mi = 0; mi < 4; ++mi) {
        #pragma unroll
        for (int ni = 0; ni < 4; ++ni) {
            int ocol = ocol_base + ni * 16 + (lane & 15);
            #pragma unroll
            for (int r = 0; r < 4; ++r) {
                int orow = orow_base + mi * 16 + (lane >> 4) * 4 + r;
                float v = acc[mi][ni][r];
                if (MODE == 0) {
                    v = fmaxf(v + bias[ocol], 0.0f);
                    ((ushort*)out0)[(size_t)orow * 256 + ocol] = f2bf(v);
                } else {
                    if (ocol < 64)
                        ((float*)out0)[(size_t)orow * 64 + ocol] = v + bias[ocol];
                    else
                        ((ushort*)out1)[(size_t)orow * 64 + (ocol - 64)] = f2bf(v);
                }
            }
        }
    }
}

// -------- final: gather-mean za (bf16) + zr + log_softmax, wave/node -----
// unrolled x4: four independent 128B row loads in flight

__global__ __launch_bounds__(256) void k_final(
    const float* __restrict__ zr, const ushort* __restrict__ za,
    const int* __restrict__ row_start, const int* __restrict__ cnt,
    const float* __restrict__ invdeg, const int* __restrict__ csr_src,
    float* __restrict__ out)
{
    int node = blockIdx.x * 4 + (threadIdx.x >> 6);
    if (node >= N_NODES) return;
    int lane = threadIdx.x & 63;
    int n = cnt[node];
    const int* cs = csr_src + row_start[node];
    float acc = 0.0f;
    int j = 0;
    for (; j + 4 <= n; j += 4) {
        int4 s4 = *(const int4*)(cs + j);
        float p0 = bf1(za[(size_t)s4.x * 64 + lane]);
        float p1 = bf1(za[(size_t)s4.y * 64 + lane]);
        float p2 = bf1(za[(size_t)s4.z * 64 + lane]);
        float p3 = bf1(za[(size_t)s4.w * 64 + lane]);
        acc += p0 + p1 + p2 + p3;
    }
    for (; j < n; ++j)
        acc += bf1(za[(size_t)cs[j] * 64 + lane]);

    float v = acc * invdeg[node] + zr[(size_t)node * 64 + lane];
    float m = v;
    #pragma unroll
    for (int o = 1; o < 64; o <<= 1) m = fmaxf(m, __shfl_xor(m, o));
    float e = expf(v - m);
    float s = e;
    #pragma unroll
    for (int o = 1; o < 64; o <<= 1) s += __shfl_xor(s, o);
    out[(size_t)node * 64 + lane] = v - m - logf(s);
}

// ---------------- launch ----------------

extern "C" void kernel_launch(void* const* d_in, const int* in_sizes, int n_in,
                              void* d_out, int out_size, void* d_ws, size_t ws_size,
                              hipStream_t stream)
{
    const float* x   = (const float*)d_in[0];
    const int*   ei  = (const int*)d_in[1];
    const float* w1a = (const float*)d_in[2];
    const float* b1  = (const float*)d_in[3];
    const float* w1r = (const float*)d_in[4];
    const float* w2a = (const float*)d_in[5];
    const float* b2  = (const float*)d_in[6];
    const float* w2r = (const float*)d_in[7];
    float* out = (float*)d_out;

    char* ws = (char*)d_ws;
    const int* src = ei;
    const int* dst = ei + N_EDGES;

    int*    cnt       = (int*)(ws + OB_CNT);
    int*    row_start = (int*)(ws + OB_RSTART);
    int*    cursor    = (int*)(ws + OB_CURSOR);
    int*    bsums     = (int*)(ws + OB_BSUMS);
    int*    csr_src   = (int*)(ws + OB_CSRC);
    float*  invdeg    = (float*)(ws + OB_INVDEG);
    ushort* xb        = (ushort*)(ws + OB_XB);
    ushort* meanb     = (ushort*)(ws + OB_MEANB);
    ushort* hb        = (ushort*)(ws + OB_HB);
    float*  zr        = (float*)(ws + OB_ZR);
    ushort* za        = (ushort*)(ws + OB_ZA);
    ushort* wcat1     = (ushort*)(ws + OB_WCAT1);
    ushort* wcat2     = (ushort*)(ws + OB_WCAT2);

    hipMemsetAsync(cnt, 0, (size_t)NPAD * 4, stream);

    k_hist<<<N_EDGES / 256, 256, 0, stream>>>(dst, cnt);
    k_scan1<<<NB_SCAN, 256, 0, stream>>>(cnt, bsums);
    k_scan2<<<1, 512, 0, stream>>>(bsums);
    k_scan3<<<NB_SCAN, 256, 0, stream>>>(cnt, bsums, row_start, cursor, invdeg);
    k_fill<<<N_EDGES / 256, 256, 0, stream>>>(src, dst, cursor, csr_src);

    k_cast_x<<<12500, 256, 0, stream>>>(x, xb);
    k_prep_w<<<384, 256, 0, stream>>>(w1a, w1r, w2r, w2a, wcat1, wcat2);

    k_gather<<<(N_NODES + 3) / 4, 256, 0, stream>>>(
        xb, row_start, cnt, csr_src, invdeg, meanb);

    dim3 g1(NROWPAD / 128, 2);
    k_gemm<128, 0><<<g1, 256, 0, stream>>>(meanb, xb, wcat1, b1, (void*)hb, nullptr);

    dim3 g2(NROWPAD / 128, 1);
    k_gemm<256, 1><<<g2, 256, 0, stream>>>(hb, hb, wcat2, b2, (void*)zr, (void*)za);

    k_final<<<(N_NODES + 3) / 4, 256, 0, stream>>>(
        zr, za, row_start, cnt, invdeg, csr_src, out);
}

// Round 5
// 227.467 us; speedup vs baseline: 16.1682x; 1.0518x over previous
//
#include <hip/hip_runtime.h>

#define N_NODES 100000
#define N_EDGES 640000
#define D_IN 128
#define D_HID 256
#define D_OUT 64

#define NPAD 100352                  // N padded to 256 (for scan)
#define NROWPAD 100096               // N padded to 128 (GEMM tiles, no guards)
#define NB_SCAN 391                  // ceil(100000/256)

// ---------------- workspace layout (byte offsets, all 16B-aligned) -------
#define OB_CNT      0u
#define OB_RSTART   401408u
#define OB_CURSOR   802816u
#define OB_BSUMS    1204224u
#define OB_CSRC     1206272u
#define OB_INVDEG   3766272u
#define OB_XB       4167680u                    // bf16 [NROWPAD][128]
#define OB_MEANB    29792256u                   // bf16 [NROWPAD][128]
#define OB_HB       55416832u                   // bf16 [NROWPAD][256]
#define OB_ZR       106665984u                  // f32  [NROWPAD][64] root+bias
#define OB_ZA       132290560u                  // bf16 [NROWPAD][64] agg half
#define OB_WCAT1    145102848u                  // bf16 [256][256]
#define OB_WCAT2    145233920u                  // bf16 [128][256]

typedef __attribute__((ext_vector_type(8))) short bf16x8;
typedef __attribute__((ext_vector_type(4))) float f32x4;

__device__ __forceinline__ ushort f2bf(float f) {
    uint u = __float_as_uint(f);
    u += 0x7FFFu + ((u >> 16) & 1u);          // round-to-nearest-even
    return (ushort)(u >> 16);
}
__device__ __forceinline__ float bf1(ushort u) { return __uint_as_float((uint)u << 16); }

// ---------------- fused prologue: cast x -> bf16 | hist | pack weights ---

__global__ __launch_bounds__(256) void k_prep(
    const float* __restrict__ x, ushort* __restrict__ xb,
    const int* __restrict__ dst, int* __restrict__ cnt,
    const float* __restrict__ w1a, const float* __restrict__ w1r,
    const float* __restrict__ w2r, const float* __restrict__ w2a,
    ushort* __restrict__ wcat1, ushort* __restrict__ wcat2)
{
    int b = blockIdx.x;
    if (b < 12500) {                  // cast x (12.8M elems, 4/thread)
        size_t i = ((size_t)b * 256 + threadIdx.x) * 4;
        float4 v = *(const float4*)(x + i);
        ushort4 o;
        o.x = f2bf(v.x); o.y = f2bf(v.y); o.z = f2bf(v.z); o.w = f2bf(v.w);
        *(ushort4*)(xb + i) = o;
    } else if (b < 15000) {           // degree histogram
        int e = (b - 12500) * 256 + threadIdx.x;
        atomicAdd(&cnt[dst[e]], 1);
    } else {                          // weight concat + cast
        int i = (b - 15000) * 256 + threadIdx.x;
        if (i < 65536) {              // wcat1 [256][256] = [w1a | w1r]
            int n = i >> 8, k = i & 255;
            float v = (k < 128) ? w1a[n * 128 + k] : w1r[n * 128 + (k - 128)];
            wcat1[i] = f2bf(v);
        } else if (i < 98304) {       // wcat2 [128][256] = [w2r ; w2a]
            int j = i - 65536;
            int n = j >> 8, k = j & 255;
            float v = (n < 64) ? w2r[n * 256 + k] : w2a[(n - 64) * 256 + k];
            wcat2[j] = f2bf(v);
        }
    }
}

// ---------------- CSR build (scan chain) ----------------

__global__ __launch_bounds__(256) void k_scan1(
    const int* __restrict__ cnt, int* __restrict__ bsums)
{
    __shared__ int s[256];
    int i = blockIdx.x * 256 + threadIdx.x;
    int v = (i < N_NODES) ? cnt[i] : 0;
    s[threadIdx.x] = v;
    __syncthreads();
    for (int o = 128; o > 0; o >>= 1) {
        if (threadIdx.x < o) s[threadIdx.x] += s[threadIdx.x + o];
        __syncthreads();
    }
    if (threadIdx.x == 0) bsums[blockIdx.x] = s[0];
}

__global__ __launch_bounds__(512) void k_scan2(int* __restrict__ bsums)
{
    __shared__ int s[512];
    int t = threadIdx.x;
    int v = (t < NB_SCAN) ? bsums[t] : 0;
    s[t] = v;
    __syncthreads();
    for (int o = 1; o < 512; o <<= 1) {
        int a = (t >= o) ? s[t - o] : 0;
        __syncthreads();
        s[t] += a;
        __syncthreads();
    }
    if (t < NB_SCAN) bsums[t] = s[t] - v;   // exclusive
}

__global__ __launch_bounds__(256) void k_scan3(
    const int* __restrict__ cnt, const int* __restrict__ bsums,
    int* __restrict__ row_start, int* __restrict__ cursor,
    float* __restrict__ invdeg)
{
    __shared__ int s[256];
    int i = blockIdx.x * 256 + threadIdx.x;
    int v = (i < N_NODES) ? cnt[i] : 0;
    s[threadIdx.x] = v;
    __syncthreads();
    for (int o = 1; o < 256; o <<= 1) {
        int a = (threadIdx.x >= o) ? s[threadIdx.x - o] : 0;
        __syncthreads();
        s[threadIdx.x] += a;
        __syncthreads();
    }
    if (i < N_NODES) {
        int excl = s[threadIdx.x] - v + bsums[blockIdx.x];
        row_start[i] = excl;
        cursor[i] = excl;
        invdeg[i] = 1.0f / fmaxf((float)v, 1.0f);
    }
}

__global__ __launch_bounds__(256) void k_fill(
    const int* __restrict__ src, const int* __restrict__ dst,
    int* __restrict__ cursor, int* __restrict__ csr_src)
{
    int e = blockIdx.x * 256 + threadIdx.x;
    int pos = atomicAdd(&cursor[dst[e]], 1);
    csr_src[pos] = src[e];
}

// ---------------- gather-mean of xb rows, one wave per node --------------
// 4 lane-groups x 16 lanes: 4 neighbors per iteration, 16B/lane loads.

__global__ __launch_bounds__(256) void k_gather(
    const ushort* __restrict__ xb, const int* __restrict__ row_start,
    const int* __restrict__ cnt, const int* __restrict__ csr_src,
    const float* __restrict__ invdeg, ushort* __restrict__ meanb)
{
    int node = blockIdx.x * 4 + (threadIdx.x >> 6);
    if (node >= N_NODES) return;
    int lane = threadIdx.x & 63;
    int g = lane >> 4, t = lane & 15;
    int n = cnt[node];
    const int* cs = csr_src + row_start[node];
    float a[8] = {};
    for (int j = 0; j < n; j += 4) {
        int jj = j + g;
        if (jj < n) {
            int s = cs[jj];
            bf16x8 v = *(const bf16x8*)(xb + (size_t)s * D_IN + t * 8);
            #pragma unroll
            for (int i = 0; i < 8; ++i) a[i] += bf1((ushort)v[i]);
        }
    }
    #pragma unroll
    for (int i = 0; i < 8; ++i) {
        a[i] += __shfl_xor(a[i], 16);
        a[i] += __shfl_xor(a[i], 32);
    }
    if (g == 0) {
        float id = invdeg[node];
        bf16x8 ov;
        #pragma unroll
        for (int i = 0; i < 8; ++i) ov[i] = (short)f2bf(a[i] * id);
        *(bf16x8*)(meanb + (size_t)node * D_IN + t * 8) = ov;
    }
}

// ---------------- MFMA GEMM: OUT[M,*] = [A0|A1] @ Bcat.T ------------------
// 128x128 tile, 4 waves (2x2), BK=64, K=256.  LDS XOR-swizzled (rule #21):
// pre-swizzled global source + linear global_load_lds dest + swizzled read.
// MODE 0: out0 = bf16 [M][256] relu(v + bias)        (layer 1)
// MODE 1: out0 = f32 [M][64] v+bias (cols 0-63), out1 = bf16 [M][64] (cols 64-127)

template<int AW, int MODE>
__global__ __launch_bounds__(256, 2) void k_gemm(
    const ushort* __restrict__ A0, const ushort* __restrict__ A1,
    const ushort* __restrict__ B,     // [*][256] bf16
    const float* __restrict__ bias,
    void* __restrict__ out0, void* __restrict__ out1)
{
    __shared__ ushort lds[2 * 128 * 64];   // A: [0,16KB), B: [16KB,32KB)

    const int tid = threadIdx.x;
    const int lane = tid & 63;
    const int w = tid >> 6;
    const int wm = w >> 1, wn = w & 1;
    const int row0 = blockIdx.x * 128;
    const int col0 = blockIdx.y * 128;

    f32x4 acc[4][4] = {};   // [mi][ni]

    for (int kt = 0; kt < 4; ++kt) {
        const int k0 = kt * 64;
        const ushort* asrc;
        int kofs;
        if (AW == 256) { asrc = A0; kofs = k0; }
        else { asrc = (k0 < 128) ? A0 : A1; kofs = k0 & 127; }

        // stage A tile [128 rows][64 bf16], 4 issues x 4KB
        #pragma unroll
        for (int i = 0; i < 4; ++i) {
            int elem = i * 256 + tid;         // 16B-chunk index
            int r = elem >> 3;                // row 0..127
            int c8 = (elem & 7) ^ (r & 7);    // swizzled source chunk
            const ushort* g = asrc + (size_t)(row0 + r) * AW + kofs + c8 * 8;
            __builtin_amdgcn_global_load_lds(
                (const __attribute__((address_space(1))) void*)g,
                (__attribute__((address_space(3))) void*)&lds[i * 2048 + w * 512],
                16, 0, 0);
        }
        // stage B tile
        #pragma unroll
        for (int i = 0; i < 4; ++i) {
            int elem = i * 256 + tid;
            int r = elem >> 3;
            int c8 = (elem & 7) ^ (r & 7);
            const ushort* g = B + (size_t)(col0 + r) * 256 + k0 + c8 * 8;
            __builtin_amdgcn_global_load_lds(
                (const __attribute__((address_space(1))) void*)g,
                (__attribute__((address_space(3))) void*)&lds[8192 + i * 2048 + w * 512],
                16, 0, 0);
        }
        asm volatile("s_waitcnt vmcnt(0)" ::: "memory");
        __syncthreads();

        #pragma unroll
        for (int ks = 0; ks < 2; ++ks) {
            bf16x8 af[4], bfr[4];
            #pragma unroll
            for (int mi = 0; mi < 4; ++mi) {
                int r = wm * 64 + mi * 16 + (lane & 15);
                int c8 = ks * 4 + (lane >> 4);
                int byteoff = r * 128 + ((c8 ^ (r & 7)) * 16);
                af[mi] = *(const bf16x8*)((const char*)lds + byteoff);
            }
            #pragma unroll
            for (int ni = 0; ni < 4; ++ni) {
                int r = wn * 64 + ni * 16 + (lane & 15);
                int c8 = ks * 4 + (lane >> 4);
                int byteoff = 16384 + r * 128 + ((c8 ^ (r & 7)) * 16);
                bfr[ni] = *(const bf16x8*)((const char*)lds + byteoff);
            }
            #pragma unroll
            for (int mi = 0; mi < 4; ++mi)
                #pragma unroll
                for (int ni = 0; ni < 4; ++ni)
                    acc[mi][ni] = __builtin_amdgcn_mfma_f32_16x16x32_bf16(
                        af[mi], bfr[ni], acc[mi][ni], 0, 0, 0);
        }
        __syncthreads();
    }

    // epilogue: C/D map col=lane&15, row=(lane>>4)*4+reg
    const int orow_base = row0 + wm * 64;
    const int ocol_base = col0 + wn * 64;
    #pragma unroll
    for (int mi = 0; mi < 4; ++mi) {
        #pragma unroll
        for (int ni = 0; ni < 4; ++ni) {
            int ocol = ocol_base + ni * 16 + (lane & 15);
            #pragma unroll
            for (int r = 0; r < 4; ++r) {
                int orow = orow_base + mi * 16 + (lane >> 4) * 4 + r;
                float v = acc[mi][ni][r];
                if (MODE == 0) {
                    v = fmaxf(v + bias[ocol], 0.0f);
                    ((ushort*)out0)[(size_t)orow * 256 + ocol] = f2bf(v);
                } else {
                    if (ocol < 64)
                        ((float*)out0)[(size_t)orow * 64 + ocol] = v + bias[ocol];
                    else
                        ((ushort*)out1)[(size_t)orow * 64 + (ocol - 64)] = f2bf(v);
                }
            }
        }
    }
}

// -------- final: gather-mean za (bf16) + zr + log_softmax, wave/node -----
// 8 lane-groups x 8 lanes: 8 neighbors per iteration, 16B/lane loads.

__global__ __launch_bounds__(256) void k_final(
    const float* __restrict__ zr, const ushort* __restrict__ za,
    const int* __restrict__ row_start, const int* __restrict__ cnt,
    const float* __restrict__ invdeg, const int* __restrict__ csr_src,
    float* __restrict__ out)
{
    int node = blockIdx.x * 4 + (threadIdx.x >> 6);
    if (node >= N_NODES) return;
    int lane = threadIdx.x & 63;
    int g = lane >> 3, t = lane & 7;
    int n = cnt[node];
    const int* cs = csr_src + row_start[node];

    float a[8] = {};
    for (int j = 0; j < n; j += 8) {
        int jj = j + g;
        if (jj < n) {
            int s = cs[jj];
            bf16x8 v = *(const bf16x8*)(za + (size_t)s * 64 + t * 8);
            #pragma unroll
            for (int i = 0; i < 8; ++i) a[i] += bf1((ushort)v[i]);
        }
    }
    #pragma unroll
    for (int i = 0; i < 8; ++i) {
        a[i] += __shfl_xor(a[i], 8);
        a[i] += __shfl_xor(a[i], 16);
        a[i] += __shfl_xor(a[i], 32);
    }

    float id = invdeg[node];
    float4 z0 = *(const float4*)(zr + (size_t)node * 64 + t * 8);
    float4 z1 = *(const float4*)(zr + (size_t)node * 64 + t * 8 + 4);
    float v0 = a[0] * id + z0.x, v1 = a[1] * id + z0.y;
    float v2 = a[2] * id + z0.z, v3 = a[3] * id + z0.w;
    float v4 = a[4] * id + z1.x, v5 = a[5] * id + z1.y;
    float v6 = a[6] * id + z1.z, v7 = a[7] * id + z1.w;

    float m = fmaxf(fmaxf(fmaxf(v0, v1), fmaxf(v2, v3)),
                    fmaxf(fmaxf(v4, v5), fmaxf(v6, v7)));
    m = fmaxf(m, __shfl_xor(m, 1));
    m = fmaxf(m, __shfl_xor(m, 2));
    m = fmaxf(m, __shfl_xor(m, 4));

    float s = expf(v0 - m) + expf(v1 - m) + expf(v2 - m) + expf(v3 - m)
            + expf(v4 - m) + expf(v5 - m) + expf(v6 - m) + expf(v7 - m);
    s += __shfl_xor(s, 1);
    s += __shfl_xor(s, 2);
    s += __shfl_xor(s, 4);
    float mls = m + logf(s);

    if (g == 0) {
        *(float4*)(out + (size_t)node * 64 + t * 8) =
            make_float4(v0 - mls, v1 - mls, v2 - mls, v3 - mls);
    } else if (g == 1) {
        *(float4*)(out + (size_t)node * 64 + t * 8 + 4) =
            make_float4(v4 - mls, v5 - mls, v6 - mls, v7 - mls);
    }
}

// ---------------- launch ----------------

extern "C" void kernel_launch(void* const* d_in, const int* in_sizes, int n_in,
                              void* d_out, int out_size, void* d_ws, size_t ws_size,
                              hipStream_t stream)
{
    const float* x   = (const float*)d_in[0];
    const int*   ei  = (const int*)d_in[1];
    const float* w1a = (const float*)d_in[2];
    const float* b1  = (const float*)d_in[3];
    const float* w1r = (const float*)d_in[4];
    const float* w2a = (const float*)d_in[5];
    const float* b2  = (const float*)d_in[6];
    const float* w2r = (const float*)d_in[7];
    float* out = (float*)d_out;

    char* ws = (char*)d_ws;
    const int* src = ei;
    const int* dst = ei + N_EDGES;

    int*    cnt       = (int*)(ws + OB_CNT);
    int*    row_start = (int*)(ws + OB_RSTART);
    int*    cursor    = (int*)(ws + OB_CURSOR);
    int*    bsums     = (int*)(ws + OB_BSUMS);
    int*    csr_src   = (int*)(ws + OB_CSRC);
    float*  invdeg    = (float*)(ws + OB_INVDEG);
    ushort* xb        = (ushort*)(ws + OB_XB);
    ushort* meanb     = (ushort*)(ws + OB_MEANB);
    ushort* hb        = (ushort*)(ws + OB_HB);
    float*  zr        = (float*)(ws + OB_ZR);
    ushort* za        = (ushort*)(ws + OB_ZA);
    ushort* wcat1     = (ushort*)(ws + OB_WCAT1);
    ushort* wcat2     = (ushort*)(ws + OB_WCAT2);

    hipMemsetAsync(cnt, 0, (size_t)NPAD * 4, stream);

    k_prep<<<15384, 256, 0, stream>>>(x, xb, dst, cnt, w1a, w1r, w2r, w2a,
                                      wcat1, wcat2);
    k_scan1<<<NB_SCAN, 256, 0, stream>>>(cnt, bsums);
    k_scan2<<<1, 512, 0, stream>>>(bsums);
    k_scan3<<<NB_SCAN, 256, 0, stream>>>(cnt, bsums, row_start, cursor, invdeg);
    k_fill<<<N_EDGES / 256, 256, 0, stream>>>(src, dst, cursor, csr_src);

    k_gather<<<(N_NODES + 3) / 4, 256, 0, stream>>>(
        xb, row_start, cnt, csr_src, invdeg, meanb);

    dim3 g1(NROWPAD / 128, 2);
    k_gemm<128, 0><<<g1, 256, 0, stream>>>(meanb, xb, wcat1, b1, (void*)hb, nullptr);

    dim3 g2(NROWPAD / 128, 1);
    k_gemm<256, 1><<<g2, 256, 0, stream>>>(hb, hb, wcat2, b2, (void*)zr, (void*)za);

    k_final<<<(N_NODES + 3) / 4, 256, 0, stream>>>(
        zr, za, row_start, cnt, invdeg, csr_src, out);
}

// Round 6
// 224.235 us; speedup vs baseline: 16.4013x; 1.0144x over previous
//
#include <hip/hip_runtime.h>

#define N_NODES 100000
#define N_EDGES 640000
#define D_IN 128
#define D_HID 256
#define D_OUT 64

#define NPAD 100352                  // N padded to 256 (for scan)
#define NROWPAD 100096               // N padded to 128 (GEMM tiles, no guards)
#define NB_SCAN 391                  // ceil(100000/256)

// ---------------- workspace layout (byte offsets, all 16B-aligned) -------
#define OB_CNT      0u
#define OB_RSTART   401408u
#define OB_CURSOR   802816u
#define OB_BSUMS    1204224u
#define OB_CSRC     1206272u
#define OB_INVDEG   3766272u
#define OB_XB       4167680u                    // bf16 [NROWPAD][128]
#define OB_MEANB    29792256u                   // bf16 [NROWPAD][128]
#define OB_HB       55416832u                   // bf16 [NROWPAD][256]
#define OB_ZR       106665984u                  // f32  [NROWPAD][64] root+bias
#define OB_ZA       132290560u                  // bf16 [NROWPAD][64] agg half
#define OB_WCAT1    145102848u                  // bf16 [256][256]
#define OB_WCAT2    145233920u                  // bf16 [128][256]

typedef __attribute__((ext_vector_type(8))) short bf16x8;
typedef __attribute__((ext_vector_type(4))) float f32x4;

__device__ __forceinline__ ushort f2bf(float f) {
    uint u = __float_as_uint(f);
    u += 0x7FFFu + ((u >> 16) & 1u);          // round-to-nearest-even
    return (ushort)(u >> 16);
}
__device__ __forceinline__ float bf1(ushort u) { return __uint_as_float((uint)u << 16); }

// ---------------- fused prologue: cast x -> bf16 | hist | pack weights ---

__global__ __launch_bounds__(256) void k_prep(
    const float* __restrict__ x, ushort* __restrict__ xb,
    const int* __restrict__ dst, int* __restrict__ cnt,
    const float* __restrict__ w1a, const float* __restrict__ w1r,
    const float* __restrict__ w2r, const float* __restrict__ w2a,
    ushort* __restrict__ wcat1, ushort* __restrict__ wcat2)
{
    int b = blockIdx.x;
    if (b < 12500) {                  // cast x (12.8M elems, 4/thread)
        size_t i = ((size_t)b * 256 + threadIdx.x) * 4;
        float4 v = *(const float4*)(x + i);
        ushort4 o;
        o.x = f2bf(v.x); o.y = f2bf(v.y); o.z = f2bf(v.z); o.w = f2bf(v.w);
        *(ushort4*)(xb + i) = o;
    } else if (b < 15000) {           // degree histogram
        int e = (b - 12500) * 256 + threadIdx.x;
        atomicAdd(&cnt[dst[e]], 1);
    } else {                          // weight concat + cast
        int i = (b - 15000) * 256 + threadIdx.x;
        if (i < 65536) {              // wcat1 [256][256] = [w1a | w1r]
            int n = i >> 8, k = i & 255;
            float v = (k < 128) ? w1a[n * 128 + k] : w1r[n * 128 + (k - 128)];
            wcat1[i] = f2bf(v);
        } else if (i < 98304) {       // wcat2 [128][256] = [w2r ; w2a]
            int j = i - 65536;
            int n = j >> 8, k = j & 255;
            float v = (n < 64) ? w2r[n * 256 + k] : w2a[(n - 64) * 256 + k];
            wcat2[j] = f2bf(v);
        }
    }
}

// ---------------- CSR build (scan chain) ----------------

__global__ __launch_bounds__(256) void k_scan1(
    const int* __restrict__ cnt, int* __restrict__ bsums)
{
    __shared__ int s[256];
    int i = blockIdx.x * 256 + threadIdx.x;
    int v = (i < N_NODES) ? cnt[i] : 0;
    s[threadIdx.x] = v;
    __syncthreads();
    for (int o = 128; o > 0; o >>= 1) {
        if (threadIdx.x < o) s[threadIdx.x] += s[threadIdx.x + o];
        __syncthreads();
    }
    if (threadIdx.x == 0) bsums[blockIdx.x] = s[0];
}

__global__ __launch_bounds__(512) void k_scan2(int* __restrict__ bsums)
{
    __shared__ int s[512];
    int t = threadIdx.x;
    int v = (t < NB_SCAN) ? bsums[t] : 0;
    s[t] = v;
    __syncthreads();
    for (int o = 1; o < 512; o <<= 1) {
        int a = (t >= o) ? s[t - o] : 0;
        __syncthreads();
        s[t] += a;
        __syncthreads();
    }
    if (t < NB_SCAN) bsums[t] = s[t] - v;   // exclusive
}

__global__ __launch_bounds__(256) void k_scan3(
    const int* __restrict__ cnt, const int* __restrict__ bsums,
    int* __restrict__ row_start, int* __restrict__ cursor,
    float* __restrict__ invdeg)
{
    __shared__ int s[256];
    int i = blockIdx.x * 256 + threadIdx.x;
    int v = (i < N_NODES) ? cnt[i] : 0;
    s[threadIdx.x] = v;
    __syncthreads();
    for (int o = 1; o < 256; o <<= 1) {
        int a = (threadIdx.x >= o) ? s[threadIdx.x - o] : 0;
        __syncthreads();
        s[threadIdx.x] += a;
        __syncthreads();
    }
    if (i < N_NODES) {
        int excl = s[threadIdx.x] - v + bsums[blockIdx.x];
        row_start[i] = excl;
        cursor[i] = excl;
        invdeg[i] = 1.0f / fmaxf((float)v, 1.0f);
    }
}

__global__ __launch_bounds__(256) void k_fill(
    const int* __restrict__ src, const int* __restrict__ dst,
    int* __restrict__ cursor, int* __restrict__ csr_src)
{
    int e = blockIdx.x * 256 + threadIdx.x;
    int pos = atomicAdd(&cursor[dst[e]], 1);
    csr_src[pos] = src[e];
}

// ---------------- gather-mean of xb rows, one wave per node --------------
// 4 lane-groups x 16 lanes; 8 neighbors in flight via masked-fma pairs.

__global__ __launch_bounds__(256) void k_gather(
    const ushort* __restrict__ xb, const int* __restrict__ row_start,
    const int* __restrict__ cnt, const int* __restrict__ csr_src,
    const float* __restrict__ invdeg, ushort* __restrict__ meanb)
{
    int node = blockIdx.x * 4 + (threadIdx.x >> 6);
    if (node >= N_NODES) return;
    int lane = threadIdx.x & 63;
    int g = lane >> 4, t = lane & 15;
    int n = cnt[node];
    const int* cs = csr_src + row_start[node];
    float a[8] = {};
    for (int j = 0; j < n; j += 8) {
        int j0 = j + g, j1 = j + g + 4;
        int i0 = (j0 < n) ? j0 : 0;
        int i1 = (j1 < n) ? j1 : 0;
        float w0 = (j0 < n) ? 1.0f : 0.0f;
        float w1 = (j1 < n) ? 1.0f : 0.0f;
        bf16x8 v0 = *(const bf16x8*)(xb + (size_t)cs[i0] * D_IN + t * 8);
        bf16x8 v1 = *(const bf16x8*)(xb + (size_t)cs[i1] * D_IN + t * 8);
        #pragma unroll
        for (int i = 0; i < 8; ++i) a[i] += w0 * bf1((ushort)v0[i]);
        #pragma unroll
        for (int i = 0; i < 8; ++i) a[i] += w1 * bf1((ushort)v1[i]);
    }
    #pragma unroll
    for (int i = 0; i < 8; ++i) {
        a[i] += __shfl_xor(a[i], 16);
        a[i] += __shfl_xor(a[i], 32);
    }
    if (g == 0) {
        float id = invdeg[node];
        bf16x8 ov;
        #pragma unroll
        for (int i = 0; i < 8; ++i) ov[i] = (short)f2bf(a[i] * id);
        *(bf16x8*)(meanb + (size_t)node * D_IN + t * 8) = ov;
    }
}

// ---------------- MFMA GEMM: OUT[M,*] = [A0|A1] @ Bcat.T ------------------
// 128x128 tile, 4 waves (2x2), BK=64, K=256.  LDS XOR-swizzled (rule #21):
// pre-swizzled global source + linear global_load_lds dest + swizzled read.
// MODE 0: out0 = bf16 [M][256] relu(v + bias)        (layer 1)
// MODE 1: out0 = f32 [M][64] v+bias (cols 0-63), out1 = bf16 [M][64] (cols 64-127)

template<int AW, int MODE>
__global__ __launch_bounds__(256, 2) void k_gemm(
    const ushort* __restrict__ A0, const ushort* __restrict__ A1,
    const ushort* __restrict__ B,     // [*][256] bf16
    const float* __restrict__ bias,
    void* __restrict__ out0, void* __restrict__ out1)
{
    __shared__ ushort lds[2 * 128 * 64];   // A: [0,16KB), B: [16KB,32KB)

    const int tid = threadIdx.x;
    const int lane = tid & 63;
    const int w = tid >> 6;
    const int wm = w >> 1, wn = w & 1;
    const int row0 = blockIdx.x * 128;
    const int col0 = blockIdx.y * 128;

    f32x4 acc[4][4] = {};   // [mi][ni]

    for (int kt = 0; kt < 4; ++kt) {
        const int k0 = kt * 64;
        const ushort* asrc;
        int kofs;
        if (AW == 256) { asrc = A0; kofs = k0; }
        else { asrc = (k0 < 128) ? A0 : A1; kofs = k0 & 127; }

        // stage A tile [128 rows][64 bf16], 4 issues x 4KB
        #pragma unroll
        for (int i = 0; i < 4; ++i) {
            int elem = i * 256 + tid;         // 16B-chunk index
            int r = elem >> 3;                // row 0..127
            int c8 = (elem & 7) ^ (r & 7);    // swizzled source chunk
            const ushort* g = asrc + (size_t)(row0 + r) * AW + kofs + c8 * 8;
            __builtin_amdgcn_global_load_lds(
                (const __attribute__((address_space(1))) void*)g,
                (__attribute__((address_space(3))) void*)&lds[i * 2048 + w * 512],
                16, 0, 0);
        }
        // stage B tile
        #pragma unroll
        for (int i = 0; i < 4; ++i) {
            int elem = i * 256 + tid;
            int r = elem >> 3;
            int c8 = (elem & 7) ^ (r & 7);
            const ushort* g = B + (size_t)(col0 + r) * 256 + k0 + c8 * 8;
            __builtin_amdgcn_global_load_lds(
                (const __attribute__((address_space(1))) void*)g,
                (__attribute__((address_space(3))) void*)&lds[8192 + i * 2048 + w * 512],
                16, 0, 0);
        }
        asm volatile("s_waitcnt vmcnt(0)" ::: "memory");
        __syncthreads();

        #pragma unroll
        for (int ks = 0; ks < 2; ++ks) {
            bf16x8 af[4], bfr[4];
            #pragma unroll
            for (int mi = 0; mi < 4; ++mi) {
                int r = wm * 64 + mi * 16 + (lane & 15);
                int c8 = ks * 4 + (lane >> 4);
                int byteoff = r * 128 + ((c8 ^ (r & 7)) * 16);
                af[mi] = *(const bf16x8*)((const char*)lds + byteoff);
            }
            #pragma unroll
            for (int ni = 0; ni < 4; ++ni) {
                int r = wn * 64 + ni * 16 + (lane & 15);
                int c8 = ks * 4 + (lane >> 4);
                int byteoff = 16384 + r * 128 + ((c8 ^ (r & 7)) * 16);
                bfr[ni] = *(const bf16x8*)((const char*)lds + byteoff);
            }
            #pragma unroll
            for (int mi = 0; mi < 4; ++mi)
                #pragma unroll
                for (int ni = 0; ni < 4; ++ni)
                    acc[mi][ni] = __builtin_amdgcn_mfma_f32_16x16x32_bf16(
                        af[mi], bfr[ni], acc[mi][ni], 0, 0, 0);
        }
        __syncthreads();
    }

    // epilogue: C/D map col=lane&15, row=(lane>>4)*4+reg
    const int orow_base = row0 + wm * 64;
    const int ocol_base = col0 + wn * 64;
    #pragma unroll
    for (int mi = 0; mi < 4; ++mi) {
        #pragma unroll
        for (int ni = 0; ni < 4; ++ni) {
            int ocol = ocol_base + ni * 16 + (lane & 15);
            #pragma unroll
            for (int r = 0; r < 4; ++r) {
                int orow = orow_base + mi * 16 + (lane >> 4) * 4 + r;
                float v = acc[mi][ni][r];
                if (MODE == 0) {
                    v = fmaxf(v + bias[ocol], 0.0f);
                    ((ushort*)out0)[(size_t)orow * 256 + ocol] = f2bf(v);
                } else {
                    if (ocol < 64)
                        ((float*)out0)[(size_t)orow * 64 + ocol] = v + bias[ocol];
                    else
                        ((ushort*)out1)[(size_t)orow * 64 + (ocol - 64)] = f2bf(v);
                }
            }
        }
    }
}

// -------- final: gather-mean za (bf16) + zr + log_softmax, wave/node -----
// neighbor-major lanes: g=lane&7 = neighbor slot, t=lane>>3 = 16B chunk.
// After xor-reduce over bits 0-2, select a[lane&7] -> lane owns class lane.

__global__ __launch_bounds__(256) void k_final(
    const float* __restrict__ zr, const ushort* __restrict__ za,
    const int* __restrict__ row_start, const int* __restrict__ cnt,
    const float* __restrict__ invdeg, const int* __restrict__ csr_src,
    float* __restrict__ out)
{
    int node = blockIdx.x * 4 + (threadIdx.x >> 6);
    if (node >= N_NODES) return;
    int lane = threadIdx.x & 63;
    int g = lane & 7, t = lane >> 3;
    int n = cnt[node];
    const int* cs = csr_src + row_start[node];

    float a[8] = {};
    for (int j = 0; j < n; j += 8) {
        int jj = j + g;
        if (jj < n) {
            int s = cs[jj];
            bf16x8 v = *(const bf16x8*)(za + (size_t)s * 64 + t * 8);
            #pragma unroll
            for (int i = 0; i < 8; ++i) a[i] += bf1((ushort)v[i]);
        }
    }
    #pragma unroll
    for (int i = 0; i < 8; ++i) {
        a[i] += __shfl_xor(a[i], 1);
        a[i] += __shfl_xor(a[i], 2);
        a[i] += __shfl_xor(a[i], 4);
    }
    // v = a[lane & 7] via cndmask tree (compile-time indices only)
    float s01 = (g & 1) ? a[1] : a[0];
    float s23 = (g & 1) ? a[3] : a[2];
    float s45 = (g & 1) ? a[5] : a[4];
    float s67 = (g & 1) ? a[7] : a[6];
    float s03 = (g & 2) ? s23 : s01;
    float s47 = (g & 2) ? s67 : s45;
    float vsel = (g & 4) ? s47 : s03;

    float v = vsel * invdeg[node] + zr[(size_t)node * 64 + lane];
    float m = v;
    #pragma unroll
    for (int o = 1; o < 64; o <<= 1) m = fmaxf(m, __shfl_xor(m, o));
    float e = __expf(v - m);
    float ssum = e;
    #pragma unroll
    for (int o = 1; o < 64; o <<= 1) ssum += __shfl_xor(ssum, o);
    out[(size_t)node * 64 + lane] = (v - m) - __logf(ssum);
}

// ---------------- launch ----------------

extern "C" void kernel_launch(void* const* d_in, const int* in_sizes, int n_in,
                              void* d_out, int out_size, void* d_ws, size_t ws_size,
                              hipStream_t stream)
{
    const float* x   = (const float*)d_in[0];
    const int*   ei  = (const int*)d_in[1];
    const float* w1a = (const float*)d_in[2];
    const float* b1  = (const float*)d_in[3];
    const float* w1r = (const float*)d_in[4];
    const float* w2a = (const float*)d_in[5];
    const float* b2  = (const float*)d_in[6];
    const float* w2r = (const float*)d_in[7];
    float* out = (float*)d_out;

    char* ws = (char*)d_ws;
    const int* src = ei;
    const int* dst = ei + N_EDGES;

    int*    cnt       = (int*)(ws + OB_CNT);
    int*    row_start = (int*)(ws + OB_RSTART);
    int*    cursor    = (int*)(ws + OB_CURSOR);
    int*    bsums     = (int*)(ws + OB_BSUMS);
    int*    csr_src   = (int*)(ws + OB_CSRC);
    float*  invdeg    = (float*)(ws + OB_INVDEG);
    ushort* xb        = (ushort*)(ws + OB_XB);
    ushort* meanb     = (ushort*)(ws + OB_MEANB);
    ushort* hb        = (ushort*)(ws + OB_HB);
    float*  zr        = (float*)(ws + OB_ZR);
    ushort* za        = (ushort*)(ws + OB_ZA);
    ushort* wcat1     = (ushort*)(ws + OB_WCAT1);
    ushort* wcat2     = (ushort*)(ws + OB_WCAT2);

    hipMemsetAsync(cnt, 0, (size_t)NPAD * 4, stream);

    k_prep<<<15384, 256, 0, stream>>>(x, xb, dst, cnt, w1a, w1r, w2r, w2a,
                                      wcat1, wcat2);
    k_scan1<<<NB_SCAN, 256, 0, stream>>>(cnt, bsums);
    k_scan2<<<1, 512, 0, stream>>>(bsums);
    k_scan3<<<NB_SCAN, 256, 0, stream>>>(cnt, bsums, row_start, cursor, invdeg);
    k_fill<<<N_EDGES / 256, 256, 0, stream>>>(src, dst, cursor, csr_src);

    k_gather<<<(N_NODES + 3) / 4, 256, 0, stream>>>(
        xb, row_start, cnt, csr_src, invdeg, meanb);

    dim3 g1(NROWPAD / 128, 2);
    k_gemm<128, 0><<<g1, 256, 0, stream>>>(meanb, xb, wcat1, b1, (void*)hb, nullptr);

    dim3 g2(NROWPAD / 128, 1);
    k_gemm<256, 1><<<g2, 256, 0, stream>>>(hb, hb, wcat2, b2, (void*)zr, (void*)za);

    k_final<<<(N_NODES + 3) / 4, 256, 0, stream>>>(
        zr, za, row_start, cnt, invdeg, csr_src, out);
}

// Round 7
// 220.907 us; speedup vs baseline: 16.6484x; 1.0151x over previous
//
#include <hip/hip_runtime.h>

#define N_NODES 100000
#define N_EDGES 640000
#define D_IN 128
#define D_HID 256
#define D_OUT 64

#define NPAD 100352                  // N padded to 256 (for scan)
#define NROWPAD 100096               // N padded to 128 (GEMM tiles, no guards)
#define NB_SCAN 391                  // ceil(100000/256)

// ---------------- workspace layout (byte offsets, all 16B-aligned) -------
#define OB_CNT      0u
#define OB_RSTART   401408u
#define OB_CURSOR   802816u
#define OB_BSUMS    1204224u
#define OB_CSRC     1206272u
#define OB_INVDEG   3766272u
#define OB_XB       4167680u                    // bf16 [NROWPAD][128]
#define OB_XQ       29792256u                   // fp8  [NROWPAD][128]
#define OB_MEANB    42604544u                   // bf16 [NROWPAD][128]
#define OB_HB       68229120u                   // bf16 [NROWPAD][256]
#define OB_ZRB      119478272u                  // bf16 [NROWPAD][64] root+bias
#define OB_ZAQ      132290560u                  // fp8  [NROWPAD][64] agg half
#define OB_WCAT1    138696704u                  // bf16 [256][256]
#define OB_WCAT2    138827776u                  // bf16 [128][256]

typedef __attribute__((ext_vector_type(8))) short bf16x8;
typedef __attribute__((ext_vector_type(4))) float f32x4;
typedef __attribute__((ext_vector_type(2))) float f32x2;

__device__ __forceinline__ ushort f2bf(float f) {
    uint u = __float_as_uint(f);
    u += 0x7FFFu + ((u >> 16) & 1u);          // round-to-nearest-even
    return (ushort)(u >> 16);
}
__device__ __forceinline__ float bf1(ushort u) { return __uint_as_float((uint)u << 16); }
__device__ __forceinline__ uchar f2q(float v) {   // f32 -> e4m3 (OCP on gfx950)
    return (uchar)(__builtin_amdgcn_cvt_pk_fp8_f32(v, v, 0, false) & 0xFF);
}

// ---------------- fused prologue: cast x -> bf16+fp8 | hist | weights ----

__global__ __launch_bounds__(256) void k_prep(
    const float* __restrict__ x, ushort* __restrict__ xb,
    uchar* __restrict__ xq,
    const int* __restrict__ dst, int* __restrict__ cnt,
    const float* __restrict__ w1a, const float* __restrict__ w1r,
    const float* __restrict__ w2r, const float* __restrict__ w2a,
    ushort* __restrict__ wcat1, ushort* __restrict__ wcat2)
{
    int b = blockIdx.x;
    if (b < 12500) {                  // cast x (12.8M elems, 4/thread)
        size_t i = ((size_t)b * 256 + threadIdx.x) * 4;
        float4 v = *(const float4*)(x + i);
        ushort4 o;
        o.x = f2bf(v.x); o.y = f2bf(v.y); o.z = f2bf(v.z); o.w = f2bf(v.w);
        *(ushort4*)(xb + i) = o;
        uint q = (uint)__builtin_amdgcn_cvt_pk_fp8_f32(v.x, v.y, 0, false);
        q = (uint)__builtin_amdgcn_cvt_pk_fp8_f32(v.z, v.w, (int)q, true);
        *(uint*)(xq + i) = q;
    } else if (b < 15000) {           // degree histogram
        int e = (b - 12500) * 256 + threadIdx.x;
        atomicAdd(&cnt[dst[e]], 1);
    } else {                          // weight concat + cast
        int i = (b - 15000) * 256 + threadIdx.x;
        if (i < 65536) {              // wcat1 [256][256] = [w1a | w1r]
            int n = i >> 8, k = i & 255;
            float v = (k < 128) ? w1a[n * 128 + k] : w1r[n * 128 + (k - 128)];
            wcat1[i] = f2bf(v);
        } else if (i < 98304) {       // wcat2 [128][256] = [w2r ; w2a]
            int j = i - 65536;
            int n = j >> 8, k = j & 255;
            float v = (n < 64) ? w2r[n * 256 + k] : w2a[(n - 64) * 256 + k];
            wcat2[j] = f2bf(v);
        }
    }
}

// ---------------- CSR build (scan chain) ----------------

__global__ __launch_bounds__(256) void k_scan1(
    const int* __restrict__ cnt, int* __restrict__ bsums)
{
    __shared__ int s[256];
    int i = blockIdx.x * 256 + threadIdx.x;
    int v = (i < N_NODES) ? cnt[i] : 0;
    s[threadIdx.x] = v;
    __syncthreads();
    for (int o = 128; o > 0; o >>= 1) {
        if (threadIdx.x < o) s[threadIdx.x] += s[threadIdx.x + o];
        __syncthreads();
    }
    if (threadIdx.x == 0) bsums[blockIdx.x] = s[0];
}

__global__ __launch_bounds__(512) void k_scan2(int* __restrict__ bsums)
{
    __shared__ int s[512];
    int t = threadIdx.x;
    int v = (t < NB_SCAN) ? bsums[t] : 0;
    s[t] = v;
    __syncthreads();
    for (int o = 1; o < 512; o <<= 1) {
        int a = (t >= o) ? s[t - o] : 0;
        __syncthreads();
        s[t] += a;
        __syncthreads();
    }
    if (t < NB_SCAN) bsums[t] = s[t] - v;   // exclusive
}

__global__ __launch_bounds__(256) void k_scan3(
    const int* __restrict__ cnt, const int* __restrict__ bsums,
    int* __restrict__ row_start, int* __restrict__ cursor,
    float* __restrict__ invdeg)
{
    __shared__ int s[256];
    int i = blockIdx.x * 256 + threadIdx.x;
    int v = (i < N_NODES) ? cnt[i] : 0;
    s[threadIdx.x] = v;
    __syncthreads();
    for (int o = 1; o < 256; o <<= 1) {
        int a = (threadIdx.x >= o) ? s[threadIdx.x - o] : 0;
        __syncthreads();
        s[threadIdx.x] += a;
        __syncthreads();
    }
    if (i < N_NODES) {
        int excl = s[threadIdx.x] - v + bsums[blockIdx.x];
        row_start[i] = excl;
        cursor[i] = excl;
        invdeg[i] = 1.0f / fmaxf((float)v, 1.0f);
    }
}

__global__ __launch_bounds__(256) void k_fill(
    const int* __restrict__ src, const int* __restrict__ dst,
    int* __restrict__ cursor, int* __restrict__ csr_src)
{
    int e = blockIdx.x * 256 + threadIdx.x;
    int pos = atomicAdd(&cursor[dst[e]], 1);
    csr_src[pos] = src[e];
}

// ---------------- gather-mean of xq (fp8) rows, one wave per node --------
// 4 lane-groups x 16 lanes; 8 neighbors in flight; 8B/lane loads.

__global__ __launch_bounds__(256) void k_gather(
    const uchar* __restrict__ xq, const int* __restrict__ row_start,
    const int* __restrict__ cnt, const int* __restrict__ csr_src,
    const float* __restrict__ invdeg, ushort* __restrict__ meanb)
{
    int node = blockIdx.x * 4 + (threadIdx.x >> 6);
    if (node >= N_NODES) return;
    int lane = threadIdx.x & 63;
    int g = lane >> 4, t = lane & 15;
    int n = cnt[node];
    const int* cs = csr_src + row_start[node];
    float a[8] = {};
    for (int j = 0; j < n; j += 8) {
        int j0 = j + g, j1 = j + g + 4;
        int i0 = (j0 < n) ? j0 : 0;
        int i1 = (j1 < n) ? j1 : 0;
        float w0 = (j0 < n) ? 1.0f : 0.0f;
        float w1 = (j1 < n) ? 1.0f : 0.0f;
        uint2 q0 = *(const uint2*)(xq + (size_t)cs[i0] * D_IN + t * 8);
        uint2 q1 = *(const uint2*)(xq + (size_t)cs[i1] * D_IN + t * 8);
        f32x2 p0 = __builtin_amdgcn_cvt_pk_f32_fp8(q0.x, false);
        f32x2 p1 = __builtin_amdgcn_cvt_pk_f32_fp8(q0.x, true);
        f32x2 p2 = __builtin_amdgcn_cvt_pk_f32_fp8(q0.y, false);
        f32x2 p3 = __builtin_amdgcn_cvt_pk_f32_fp8(q0.y, true);
        a[0] += w0 * p0.x; a[1] += w0 * p0.y; a[2] += w0 * p1.x; a[3] += w0 * p1.y;
        a[4] += w0 * p2.x; a[5] += w0 * p2.y; a[6] += w0 * p3.x; a[7] += w0 * p3.y;
        p0 = __builtin_amdgcn_cvt_pk_f32_fp8(q1.x, false);
        p1 = __builtin_amdgcn_cvt_pk_f32_fp8(q1.x, true);
        p2 = __builtin_amdgcn_cvt_pk_f32_fp8(q1.y, false);
        p3 = __builtin_amdgcn_cvt_pk_f32_fp8(q1.y, true);
        a[0] += w1 * p0.x; a[1] += w1 * p0.y; a[2] += w1 * p1.x; a[3] += w1 * p1.y;
        a[4] += w1 * p2.x; a[5] += w1 * p2.y; a[6] += w1 * p3.x; a[7] += w1 * p3.y;
    }
    #pragma unroll
    for (int i = 0; i < 8; ++i) {
        a[i] += __shfl_xor(a[i], 16);
        a[i] += __shfl_xor(a[i], 32);
    }
    if (g == 0) {
        float id = invdeg[node];
        bf16x8 ov;
        #pragma unroll
        for (int i = 0; i < 8; ++i) ov[i] = (short)f2bf(a[i] * id);
        *(bf16x8*)(meanb + (size_t)node * D_IN + t * 8) = ov;
    }
}

// ---------------- MFMA GEMM: OUT[M,*] = [A0|A1] @ Bcat.T ------------------
// 128x128 tile, 4 waves (2x2), BK=64, K=256.  LDS XOR-swizzled (rule #21):
// pre-swizzled global source + linear global_load_lds dest + swizzled read.
// MODE 0: out0 = bf16 [M][256] relu(v + bias)        (layer 1)
// MODE 1: out0 = bf16 [M][64] v+bias (cols 0-63), out1 = fp8 [M][64] (cols 64-127)

template<int AW, int MODE>
__global__ __launch_bounds__(256, 2) void k_gemm(
    const ushort* __restrict__ A0, const ushort* __restrict__ A1,
    const ushort* __restrict__ B,     // [*][256] bf16
    const float* __restrict__ bias,
    void* __restrict__ out0, void* __restrict__ out1)
{
    __shared__ ushort lds[2 * 128 * 64];   // A: [0,16KB), B: [16KB,32KB)

    const int tid = threadIdx.x;
    const int lane = tid & 63;
    const int w = tid >> 6;
    const int wm = w >> 1, wn = w & 1;
    const int row0 = blockIdx.x * 128;
    const int col0 = blockIdx.y * 128;

    f32x4 acc[4][4] = {};   // [mi][ni]

    for (int kt = 0; kt < 4; ++kt) {
        const int k0 = kt * 64;
        const ushort* asrc;
        int kofs;
        if (AW == 256) { asrc = A0; kofs = k0; }
        else { asrc = (k0 < 128) ? A0 : A1; kofs = k0 & 127; }

        // stage A tile [128 rows][64 bf16], 4 issues x 4KB
        #pragma unroll
        for (int i = 0; i < 4; ++i) {
            int elem = i * 256 + tid;         // 16B-chunk index
            int r = elem >> 3;                // row 0..127
            int c8 = (elem & 7) ^ (r & 7);    // swizzled source chunk
            const ushort* g = asrc + (size_t)(row0 + r) * AW + kofs + c8 * 8;
            __builtin_amdgcn_global_load_lds(
                (const __attribute__((address_space(1))) void*)g,
                (__attribute__((address_space(3))) void*)&lds[i * 2048 + w * 512],
                16, 0, 0);
        }
        // stage B tile
        #pragma unroll
        for (int i = 0; i < 4; ++i) {
            int elem = i * 256 + tid;
            int r = elem >> 3;
            int c8 = (elem & 7) ^ (r & 7);
            const ushort* g = B + (size_t)(col0 + r) * 256 + k0 + c8 * 8;
            __builtin_amdgcn_global_load_lds(
                (const __attribute__((address_space(1))) void*)g,
                (__attribute__((address_space(3))) void*)&lds[8192 + i * 2048 + w * 512],
                16, 0, 0);
        }
        asm volatile("s_waitcnt vmcnt(0)" ::: "memory");
        __syncthreads();

        #pragma unroll
        for (int ks = 0; ks < 2; ++ks) {
            bf16x8 af[4], bfr[4];
            #pragma unroll
            for (int mi = 0; mi < 4; ++mi) {
                int r = wm * 64 + mi * 16 + (lane & 15);
                int c8 = ks * 4 + (lane >> 4);
                int byteoff = r * 128 + ((c8 ^ (r & 7)) * 16);
                af[mi] = *(const bf16x8*)((const char*)lds + byteoff);
            }
            #pragma unroll
            for (int ni = 0; ni < 4; ++ni) {
                int r = wn * 64 + ni * 16 + (lane & 15);
                int c8 = ks * 4 + (lane >> 4);
                int byteoff = 16384 + r * 128 + ((c8 ^ (r & 7)) * 16);
                bfr[ni] = *(const bf16x8*)((const char*)lds + byteoff);
            }
            #pragma unroll
            for (int mi = 0; mi < 4; ++mi)
                #pragma unroll
                for (int ni = 0; ni < 4; ++ni)
                    acc[mi][ni] = __builtin_amdgcn_mfma_f32_16x16x32_bf16(
                        af[mi], bfr[ni], acc[mi][ni], 0, 0, 0);
        }
        __syncthreads();
    }

    // epilogue: C/D map col=lane&15, row=(lane>>4)*4+reg
    const int orow_base = row0 + wm * 64;
    const int ocol_base = col0 + wn * 64;
    #pragma unroll
    for (int mi = 0; mi < 4; ++mi) {
        #pragma unroll
        for (int ni = 0; ni < 4; ++ni) {
            int ocol = ocol_base + ni * 16 + (lane & 15);
            #pragma unroll
            for (int r = 0; r < 4; ++r) {
                int orow = orow_base + mi * 16 + (lane >> 4) * 4 + r;
                float v = acc[mi][ni][r];
                if (MODE == 0) {
                    v = fmaxf(v + bias[ocol], 0.0f);
                    ((ushort*)out0)[(size_t)orow * 256 + ocol] = f2bf(v);
                } else {
                    if (ocol < 64)
                        ((ushort*)out0)[(size_t)orow * 64 + ocol] = f2bf(v + bias[ocol]);
                    else
                        ((uchar*)out1)[(size_t)orow * 64 + (ocol - 64)] = f2q(v);
                }
            }
        }
    }
}

// -------- final: gather-mean zaq (fp8) + zrb + log_softmax, wave/node ----
// neighbor-major lanes: g=lane&7 = neighbor slot, t=lane>>3 = 8B chunk.
// After xor-reduce over bits 0-2, select a[lane&7] -> lane owns class lane.

__global__ __launch_bounds__(256) void k_final(
    const ushort* __restrict__ zrb, const uchar* __restrict__ zaq,
    const int* __restrict__ row_start, const int* __restrict__ cnt,
    const float* __restrict__ invdeg, const int* __restrict__ csr_src,
    float* __restrict__ out)
{
    int node = blockIdx.x * 4 + (threadIdx.x >> 6);
    if (node >= N_NODES) return;
    int lane = threadIdx.x & 63;
    int g = lane & 7, t = lane >> 3;
    int n = cnt[node];
    const int* cs = csr_src + row_start[node];

    float a[8] = {};
    for (int j = 0; j < n; j += 8) {
        int jj = j + g;
        if (jj < n) {
            int s = cs[jj];
            uint2 q = *(const uint2*)(zaq + (size_t)s * 64 + t * 8);
            f32x2 p0 = __builtin_amdgcn_cvt_pk_f32_fp8(q.x, false);
            f32x2 p1 = __builtin_amdgcn_cvt_pk_f32_fp8(q.x, true);
            f32x2 p2 = __builtin_amdgcn_cvt_pk_f32_fp8(q.y, false);
            f32x2 p3 = __builtin_amdgcn_cvt_pk_f32_fp8(q.y, true);
            a[0] += p0.x; a[1] += p0.y; a[2] += p1.x; a[3] += p1.y;
            a[4] += p2.x; a[5] += p2.y; a[6] += p3.x; a[7] += p3.y;
        }
    }
    #pragma unroll
    for (int i = 0; i < 8; ++i) {
        a[i] += __shfl_xor(a[i], 1);
        a[i] += __shfl_xor(a[i], 2);
        a[i] += __shfl_xor(a[i], 4);
    }
    // v = a[lane & 7] via cndmask tree (compile-time indices only)
    float s01 = (g & 1) ? a[1] : a[0];
    float s23 = (g & 1) ? a[3] : a[2];
    float s45 = (g & 1) ? a[5] : a[4];
    float s67 = (g & 1) ? a[7] : a[6];
    float s03 = (g & 2) ? s23 : s01;
    float s47 = (g & 2) ? s67 : s45;
    float vsel = (g & 4) ? s47 : s03;

    float v = vsel * invdeg[node] + bf1(zrb[(size_t)node * 64 + lane]);
    float m = v;
    #pragma unroll
    for (int o = 1; o < 64; o <<= 1) m = fmaxf(m, __shfl_xor(m, o));
    float e = __expf(v - m);
    float ssum = e;
    #pragma unroll
    for (int o = 1; o < 64; o <<= 1) ssum += __shfl_xor(ssum, o);
    out[(size_t)node * 64 + lane] = (v - m) - __logf(ssum);
}

// ---------------- launch ----------------

extern "C" void kernel_launch(void* const* d_in, const int* in_sizes, int n_in,
                              void* d_out, int out_size, void* d_ws, size_t ws_size,
                              hipStream_t stream)
{
    const float* x   = (const float*)d_in[0];
    const int*   ei  = (const int*)d_in[1];
    const float* w1a = (const float*)d_in[2];
    const float* b1  = (const float*)d_in[3];
    const float* w1r = (const float*)d_in[4];
    const float* w2a = (const float*)d_in[5];
    const float* b2  = (const float*)d_in[6];
    const float* w2r = (const float*)d_in[7];
    float* out = (float*)d_out;

    char* ws = (char*)d_ws;
    const int* src = ei;
    const int* dst = ei + N_EDGES;

    int*    cnt       = (int*)(ws + OB_CNT);
    int*    row_start = (int*)(ws + OB_RSTART);
    int*    cursor    = (int*)(ws + OB_CURSOR);
    int*    bsums     = (int*)(ws + OB_BSUMS);
    int*    csr_src   = (int*)(ws + OB_CSRC);
    float*  invdeg    = (float*)(ws + OB_INVDEG);
    ushort* xb        = (ushort*)(ws + OB_XB);
    uchar*  xq        = (uchar*)(ws + OB_XQ);
    ushort* meanb     = (ushort*)(ws + OB_MEANB);
    ushort* hb        = (ushort*)(ws + OB_HB);
    ushort* zrb       = (ushort*)(ws + OB_ZRB);
    uchar*  zaq       = (uchar*)(ws + OB_ZAQ);
    ushort* wcat1     = (ushort*)(ws + OB_WCAT1);
    ushort* wcat2     = (ushort*)(ws + OB_WCAT2);

    hipMemsetAsync(cnt, 0, (size_t)NPAD * 4, stream);

    k_prep<<<15384, 256, 0, stream>>>(x, xb, xq, dst, cnt, w1a, w1r, w2r, w2a,
                                      wcat1, wcat2);
    k_scan1<<<NB_SCAN, 256, 0, stream>>>(cnt, bsums);
    k_scan2<<<1, 512, 0, stream>>>(bsums);
    k_scan3<<<NB_SCAN, 256, 0, stream>>>(cnt, bsums, row_start, cursor, invdeg);
    k_fill<<<N_EDGES / 256, 256, 0, stream>>>(src, dst, cursor, csr_src);

    k_gather<<<(N_NODES + 3) / 4, 256, 0, stream>>>(
        xq, row_start, cnt, csr_src, invdeg, meanb);

    dim3 g1(NROWPAD / 128, 2);
    k_gemm<128, 0><<<g1, 256, 0, stream>>>(meanb, xb, wcat1, b1, (void*)hb, nullptr);

    dim3 g2(NROWPAD / 128, 1);
    k_gemm<256, 1><<<g2, 256, 0, stream>>>(hb, hb, wcat2, b2, (void*)zrb, (void*)zaq);

    k_final<<<(N_NODES + 3) / 4, 256, 0, stream>>>(
        zrb, zaq, row_start, cnt, invdeg, csr_src, out);
}

// Round 8
// 202.317 us; speedup vs baseline: 18.1781x; 1.0919x over previous
//
#include <hip/hip_runtime.h>

#define N_NODES 100000
#define N_EDGES 640000
#define D_IN 128
#define D_HID 256
#define D_OUT 64

#define NPAD 100352                  // N padded to 256 (for scan)
#define NROWPAD 100096               // N padded to 128 (GEMM tiles, no guards)
#define NB_SCAN 391                  // ceil(100000/256)

// ---------------- workspace layout (byte offsets, all 16B-aligned) -------
#define OB_CNT      0u
#define OB_RSTART   401408u
#define OB_CURSOR   802816u
#define OB_BSUMS    1204224u
#define OB_CSRC     1206272u
#define OB_INVDEG   3766272u
#define OB_XB       4167680u                    // bf16 [NROWPAD][128]
#define OB_XQ       29792256u                   // fp8  [NROWPAD][128]
#define OB_MEANB    42604544u                   // bf16 [NROWPAD][128]
#define OB_HB       68229120u                   // bf16 [NROWPAD][256]
#define OB_ZRB      119478272u                  // bf16 [NROWPAD][64] root+bias
#define OB_ZAQ      132290560u                  // fp8  [NROWPAD][64] agg half
#define OB_WCAT1    138696704u                  // bf16 [256][256]
#define OB_WCAT2    138827776u                  // bf16 [128][256]

typedef __attribute__((ext_vector_type(8))) short bf16x8;
typedef __attribute__((ext_vector_type(4))) float f32x4;
typedef __attribute__((ext_vector_type(2))) float f32x2;

__device__ __forceinline__ ushort f2bf(float f) {
    uint u = __float_as_uint(f);
    u += 0x7FFFu + ((u >> 16) & 1u);          // round-to-nearest-even
    return (ushort)(u >> 16);
}
__device__ __forceinline__ float bf1(ushort u) { return __uint_as_float((uint)u << 16); }
__device__ __forceinline__ uchar f2q(float v) {   // f32 -> e4m3 (OCP on gfx950)
    return (uchar)(__builtin_amdgcn_cvt_pk_fp8_f32(v, v, 0, false) & 0xFF);
}

// ---------------- fused prologue: cast x -> bf16+fp8 | hist | weights ----

__global__ __launch_bounds__(256) void k_prep(
    const float* __restrict__ x, ushort* __restrict__ xb,
    uchar* __restrict__ xq,
    const int* __restrict__ dst, int* __restrict__ cnt,
    const float* __restrict__ w1a, const float* __restrict__ w1r,
    const float* __restrict__ w2r, const float* __restrict__ w2a,
    ushort* __restrict__ wcat1, ushort* __restrict__ wcat2)
{
    int b = blockIdx.x;
    if (b < 12500) {                  // cast x (12.8M elems, 4/thread)
        size_t i = ((size_t)b * 256 + threadIdx.x) * 4;
        float4 v = *(const float4*)(x + i);
        ushort4 o;
        o.x = f2bf(v.x); o.y = f2bf(v.y); o.z = f2bf(v.z); o.w = f2bf(v.w);
        *(ushort4*)(xb + i) = o;
        uint q = (uint)__builtin_amdgcn_cvt_pk_fp8_f32(v.x, v.y, 0, false);
        q = (uint)__builtin_amdgcn_cvt_pk_fp8_f32(v.z, v.w, (int)q, true);
        *(uint*)(xq + i) = q;
    } else if (b < 15000) {           // degree histogram
        int e = (b - 12500) * 256 + threadIdx.x;
        atomicAdd(&cnt[dst[e]], 1);
    } else {                          // weight concat + cast
        int i = (b - 15000) * 256 + threadIdx.x;
        if (i < 65536) {              // wcat1 [256][256] = [w1a | w1r]
            int n = i >> 8, k = i & 255;
            float v = (k < 128) ? w1a[n * 128 + k] : w1r[n * 128 + (k - 128)];
            wcat1[i] = f2bf(v);
        } else if (i < 98304) {       // wcat2 [128][256] = [w2r ; w2a]
            int j = i - 65536;
            int n = j >> 8, k = j & 255;
            float v = (n < 64) ? w2r[n * 256 + k] : w2a[(n - 64) * 256 + k];
            wcat2[j] = f2bf(v);
        }
    }
}

// ---------------- CSR build (scan chain) ----------------

__global__ __launch_bounds__(256) void k_scan1(
    const int* __restrict__ cnt, int* __restrict__ bsums)
{
    __shared__ int s[256];
    int i = blockIdx.x * 256 + threadIdx.x;
    int v = (i < N_NODES) ? cnt[i] : 0;
    s[threadIdx.x] = v;
    __syncthreads();
    for (int o = 128; o > 0; o >>= 1) {
        if (threadIdx.x < o) s[threadIdx.x] += s[threadIdx.x + o];
        __syncthreads();
    }
    if (threadIdx.x == 0) bsums[blockIdx.x] = s[0];
}

__global__ __launch_bounds__(512) void k_scan2(int* __restrict__ bsums)
{
    __shared__ int s[512];
    int t = threadIdx.x;
    int v = (t < NB_SCAN) ? bsums[t] : 0;
    s[t] = v;
    __syncthreads();
    for (int o = 1; o < 512; o <<= 1) {
        int a = (t >= o) ? s[t - o] : 0;
        __syncthreads();
        s[t] += a;
        __syncthreads();
    }
    if (t < NB_SCAN) bsums[t] = s[t] - v;   // exclusive
}

__global__ __launch_bounds__(256) void k_scan3(
    const int* __restrict__ cnt, const int* __restrict__ bsums,
    int* __restrict__ row_start, int* __restrict__ cursor,
    float* __restrict__ invdeg)
{
    __shared__ int s[256];
    int i = blockIdx.x * 256 + threadIdx.x;
    int v = (i < N_NODES) ? cnt[i] : 0;
    s[threadIdx.x] = v;
    __syncthreads();
    for (int o = 1; o < 256; o <<= 1) {
        int a = (threadIdx.x >= o) ? s[threadIdx.x - o] : 0;
        __syncthreads();
        s[threadIdx.x] += a;
        __syncthreads();
    }
    if (i < N_NODES) {
        int excl = s[threadIdx.x] - v + bsums[blockIdx.x];
        row_start[i] = excl;
        cursor[i] = excl;
        invdeg[i] = 1.0f / fmaxf((float)v, 1.0f);
    }
}

__global__ __launch_bounds__(256) void k_fill(
    const int* __restrict__ src, const int* __restrict__ dst,
    int* __restrict__ cursor, int* __restrict__ csr_src)
{
    int e = blockIdx.x * 256 + threadIdx.x;
    int pos = atomicAdd(&cursor[dst[e]], 1);
    csr_src[pos] = src[e];
}

// ---------------- gather-mean of xq (fp8) rows, one wave per node --------
// 4 lane-groups x 16 lanes; 8 neighbors in flight; 8B/lane loads.

__global__ __launch_bounds__(256) void k_gather(
    const uchar* __restrict__ xq, const int* __restrict__ row_start,
    const int* __restrict__ cnt, const int* __restrict__ csr_src,
    const float* __restrict__ invdeg, ushort* __restrict__ meanb)
{
    int node = blockIdx.x * 4 + (threadIdx.x >> 6);
    if (node >= N_NODES) return;
    int lane = threadIdx.x & 63;
    int g = lane >> 4, t = lane & 15;
    int n = cnt[node];
    const int* cs = csr_src + row_start[node];
    float a[8] = {};
    for (int j = 0; j < n; j += 8) {
        int j0 = j + g, j1 = j + g + 4;
        int i0 = (j0 < n) ? j0 : 0;
        int i1 = (j1 < n) ? j1 : 0;
        float w0 = (j0 < n) ? 1.0f : 0.0f;
        float w1 = (j1 < n) ? 1.0f : 0.0f;
        uint2 q0 = *(const uint2*)(xq + (size_t)cs[i0] * D_IN + t * 8);
        uint2 q1 = *(const uint2*)(xq + (size_t)cs[i1] * D_IN + t * 8);
        f32x2 p0 = __builtin_amdgcn_cvt_pk_f32_fp8(q0.x, false);
        f32x2 p1 = __builtin_amdgcn_cvt_pk_f32_fp8(q0.x, true);
        f32x2 p2 = __builtin_amdgcn_cvt_pk_f32_fp8(q0.y, false);
        f32x2 p3 = __builtin_amdgcn_cvt_pk_f32_fp8(q0.y, true);
        a[0] += w0 * p0.x; a[1] += w0 * p0.y; a[2] += w0 * p1.x; a[3] += w0 * p1.y;
        a[4] += w0 * p2.x; a[5] += w0 * p2.y; a[6] += w0 * p3.x; a[7] += w0 * p3.y;
        p0 = __builtin_amdgcn_cvt_pk_f32_fp8(q1.x, false);
        p1 = __builtin_amdgcn_cvt_pk_f32_fp8(q1.x, true);
        p2 = __builtin_amdgcn_cvt_pk_f32_fp8(q1.y, false);
        p3 = __builtin_amdgcn_cvt_pk_f32_fp8(q1.y, true);
        a[0] += w1 * p0.x; a[1] += w1 * p0.y; a[2] += w1 * p1.x; a[3] += w1 * p1.y;
        a[4] += w1 * p2.x; a[5] += w1 * p2.y; a[6] += w1 * p3.x; a[7] += w1 * p3.y;
    }
    #pragma unroll
    for (int i = 0; i < 8; ++i) {
        a[i] += __shfl_xor(a[i], 16);
        a[i] += __shfl_xor(a[i], 32);
    }
    if (g == 0) {
        float id = invdeg[node];
        bf16x8 ov;
        #pragma unroll
        for (int i = 0; i < 8; ++i) ov[i] = (short)f2bf(a[i] * id);
        *(bf16x8*)(meanb + (size_t)node * D_IN + t * 8) = ov;
    }
}

// ---------------- MFMA GEMM: OUT[M,*] = [A0|A1] @ Bcat.T ------------------
// 128x128 tile, 4 waves (2x2), BK=64, K=256.  LDS XOR-swizzled (rule #21):
// pre-swizzled global source + linear global_load_lds dest + swizzled read.
// MODE 0: out0 = bf16 [M][256] relu(v + bias)        (layer 1)
// MODE 1: out0 = bf16 [M][64] v+bias (cols 0-63), out1 = fp8 [M][64] (cols 64-127)

template<int AW, int MODE>
__global__ __launch_bounds__(256, 2) void k_gemm(
    const ushort* __restrict__ A0, const ushort* __restrict__ A1,
    const ushort* __restrict__ B,     // [*][256] bf16
    const float* __restrict__ bias,
    void* __restrict__ out0, void* __restrict__ out1)
{
    __shared__ ushort lds[2 * 128 * 64];   // A: [0,16KB), B: [16KB,32KB)

    const int tid = threadIdx.x;
    const int lane = tid & 63;
    const int w = tid >> 6;
    const int wm = w >> 1, wn = w & 1;
    const int row0 = blockIdx.x * 128;
    const int col0 = blockIdx.y * 128;

    f32x4 acc[4][4] = {};   // [mi][ni]

    for (int kt = 0; kt < 4; ++kt) {
        const int k0 = kt * 64;
        const ushort* asrc;
        int kofs;
        if (AW == 256) { asrc = A0; kofs = k0; }
        else { asrc = (k0 < 128) ? A0 : A1; kofs = k0 & 127; }

        // stage A tile [128 rows][64 bf16], 4 issues x 4KB
        #pragma unroll
        for (int i = 0; i < 4; ++i) {
            int elem = i * 256 + tid;         // 16B-chunk index
            int r = elem >> 3;                // row 0..127
            int c8 = (elem & 7) ^ (r & 7);    // swizzled source chunk
            const ushort* g = asrc + (size_t)(row0 + r) * AW + kofs + c8 * 8;
            __builtin_amdgcn_global_load_lds(
                (const __attribute__((address_space(1))) void*)g,
                (__attribute__((address_space(3))) void*)&lds[i * 2048 + w * 512],
                16, 0, 0);
        }
        // stage B tile
        #pragma unroll
        for (int i = 0; i < 4; ++i) {
            int elem = i * 256 + tid;
            int r = elem >> 3;
            int c8 = (elem & 7) ^ (r & 7);
            const ushort* g = B + (size_t)(col0 + r) * 256 + k0 + c8 * 8;
            __builtin_amdgcn_global_load_lds(
                (const __attribute__((address_space(1))) void*)g,
                (__attribute__((address_space(3))) void*)&lds[8192 + i * 2048 + w * 512],
                16, 0, 0);
        }
        asm volatile("s_waitcnt vmcnt(0)" ::: "memory");
        __syncthreads();

        #pragma unroll
        for (int ks = 0; ks < 2; ++ks) {
            bf16x8 af[4], bfr[4];
            #pragma unroll
            for (int mi = 0; mi < 4; ++mi) {
                int r = wm * 64 + mi * 16 + (lane & 15);
                int c8 = ks * 4 + (lane >> 4);
                int byteoff = r * 128 + ((c8 ^ (r & 7)) * 16);
                af[mi] = *(const bf16x8*)((const char*)lds + byteoff);
            }
            #pragma unroll
            for (int ni = 0; ni < 4; ++ni) {
                int r = wn * 64 + ni * 16 + (lane & 15);
                int c8 = ks * 4 + (lane >> 4);
                int byteoff = 16384 + r * 128 + ((c8 ^ (r & 7)) * 16);
                bfr[ni] = *(const bf16x8*)((const char*)lds + byteoff);
            }
            #pragma unroll
            for (int mi = 0; mi < 4; ++mi)
                #pragma unroll
                for (int ni = 0; ni < 4; ++ni)
                    acc[mi][ni] = __builtin_amdgcn_mfma_f32_16x16x32_bf16(
                        af[mi], bfr[ni], acc[mi][ni], 0, 0, 0);
        }
        __syncthreads();
    }

    // epilogue: C/D map col=lane&15, row=(lane>>4)*4+reg
    const int orow_base = row0 + wm * 64;
    const int ocol_base = col0 + wn * 64;
    #pragma unroll
    for (int mi = 0; mi < 4; ++mi) {
        #pragma unroll
        for (int ni = 0; ni < 4; ++ni) {
            int ocol = ocol_base + ni * 16 + (lane & 15);
            #pragma unroll
            for (int r = 0; r < 4; ++r) {
                int orow = orow_base + mi * 16 + (lane >> 4) * 4 + r;
                float v = acc[mi][ni][r];
                if (MODE == 0) {
                    v = fmaxf(v + bias[ocol], 0.0f);
                    ((ushort*)out0)[(size_t)orow * 256 + ocol] = f2bf(v);
                } else {
                    if (ocol < 64)
                        ((ushort*)out0)[(size_t)orow * 64 + ocol] = f2bf(v + bias[ocol]);
                    else
                        ((uchar*)out1)[(size_t)orow * 64 + (ocol - 64)] = f2q(v);
                }
            }
        }
    }
}

// -------- final: gather-mean zaq (fp8) + zrb + log_softmax ---------------
// TWO nodes per wave (32 lanes each).  Within a node: slot g=l&7 (8
// neighbors/iter), chunk t=l>>3 (16B of the 64B zaq row).  Butterfly
// register-halving reduce over lane bits 0-2; lane ends with classes
// t*16+(l&7) and +8.  Softmax over the 32-lane half.

__global__ __launch_bounds__(256) void k_final(
    const ushort* __restrict__ zrb, const uchar* __restrict__ zaq,
    const int* __restrict__ row_start, const int* __restrict__ cnt,
    const float* __restrict__ invdeg, const int* __restrict__ csr_src,
    float* __restrict__ out)
{
    int tid = threadIdx.x;
    int lane = tid & 63;
    int l = lane & 31;
    int node = blockIdx.x * 8 + (tid >> 5);   // 12500*8 = 100000 exactly
    int g = l & 7, t = l >> 3;
    int n = cnt[node];
    const int* cs = csr_src + row_start[node];

    float a[16] = {};
    for (int j = 0; j < n; j += 8) {
        int jj = j + g;
        int ii = (jj < n) ? jj : 0;
        float w = (jj < n) ? 1.0f : 0.0f;
        int s = cs[ii];
        uint4 q = *(const uint4*)(zaq + (size_t)s * 64 + t * 16);
        f32x2 p;
        p = __builtin_amdgcn_cvt_pk_f32_fp8(q.x, false); a[0] += w*p.x; a[1] += w*p.y;
        p = __builtin_amdgcn_cvt_pk_f32_fp8(q.x, true);  a[2] += w*p.x; a[3] += w*p.y;
        p = __builtin_amdgcn_cvt_pk_f32_fp8(q.y, false); a[4] += w*p.x; a[5] += w*p.y;
        p = __builtin_amdgcn_cvt_pk_f32_fp8(q.y, true);  a[6] += w*p.x; a[7] += w*p.y;
        p = __builtin_amdgcn_cvt_pk_f32_fp8(q.z, false); a[8] += w*p.x; a[9] += w*p.y;
        p = __builtin_amdgcn_cvt_pk_f32_fp8(q.z, true);  a[10]+= w*p.x; a[11]+= w*p.y;
        p = __builtin_amdgcn_cvt_pk_f32_fp8(q.w, false); a[12]+= w*p.x; a[13]+= w*p.y;
        p = __builtin_amdgcn_cvt_pk_f32_fp8(q.w, true);  a[14]+= w*p.x; a[15]+= w*p.y;
    }

    // butterfly reduce over lane bits 0..2, halving registers each stage
    float b[8];
    #pragma unroll
    for (int j = 0; j < 8; ++j) {
        float mine = (l & 1) ? a[2*j+1] : a[2*j];
        float send = (l & 1) ? a[2*j]   : a[2*j+1];
        b[j] = mine + __shfl_xor(send, 1);
    }
    float c[4];
    #pragma unroll
    for (int j = 0; j < 4; ++j) {
        float mine = (l & 2) ? b[2*j+1] : b[2*j];
        float send = (l & 2) ? b[2*j]   : b[2*j+1];
        c[j] = mine + __shfl_xor(send, 2);
    }
    float m0 = (l & 4) ? c[1] : c[0];
    float s0 = (l & 4) ? c[0] : c[1];
    float e0 = m0 + __shfl_xor(s0, 4);
    float m1 = (l & 4) ? c[3] : c[2];
    float s1 = (l & 4) ? c[2] : c[3];
    float e1 = m1 + __shfl_xor(s1, 4);

    int c0 = t * 16 + (l & 7);
    float id = invdeg[node];
    float v0 = e0 * id + bf1(zrb[(size_t)node * 64 + c0]);
    float v1 = e1 * id + bf1(zrb[(size_t)node * 64 + c0 + 8]);

    float m = fmaxf(v0, v1);
    #pragma unroll
    for (int o = 1; o < 32; o <<= 1) m = fmaxf(m, __shfl_xor(m, o));
    float ssum = __expf(v0 - m) + __expf(v1 - m);
    #pragma unroll
    for (int o = 1; o < 32; o <<= 1) ssum += __shfl_xor(ssum, o);
    float lse = m + __logf(ssum);

    out[(size_t)node * 64 + c0]     = v0 - lse;
    out[(size_t)node * 64 + c0 + 8] = v1 - lse;
}

// ---------------- launch ----------------

extern "C" void kernel_launch(void* const* d_in, const int* in_sizes, int n_in,
                              void* d_out, int out_size, void* d_ws, size_t ws_size,
                              hipStream_t stream)
{
    const float* x   = (const float*)d_in[0];
    const int*   ei  = (const int*)d_in[1];
    const float* w1a = (const float*)d_in[2];
    const float* b1  = (const float*)d_in[3];
    const float* w1r = (const float*)d_in[4];
    const float* w2a = (const float*)d_in[5];
    const float* b2  = (const float*)d_in[6];
    const float* w2r = (const float*)d_in[7];
    float* out = (float*)d_out;

    char* ws = (char*)d_ws;
    const int* src = ei;
    const int* dst = ei + N_EDGES;

    int*    cnt       = (int*)(ws + OB_CNT);
    int*    row_start = (int*)(ws + OB_RSTART);
    int*    cursor    = (int*)(ws + OB_CURSOR);
    int*    bsums     = (int*)(ws + OB_BSUMS);
    int*    csr_src   = (int*)(ws + OB_CSRC);
    float*  invdeg    = (float*)(ws + OB_INVDEG);
    ushort* xb        = (ushort*)(ws + OB_XB);
    uchar*  xq        = (uchar*)(ws + OB_XQ);
    ushort* meanb     = (ushort*)(ws + OB_MEANB);
    ushort* hb        = (ushort*)(ws + OB_HB);
    ushort* zrb       = (ushort*)(ws + OB_ZRB);
    uchar*  zaq       = (uchar*)(ws + OB_ZAQ);
    ushort* wcat1     = (ushort*)(ws + OB_WCAT1);
    ushort* wcat2     = (ushort*)(ws + OB_WCAT2);

    hipMemsetAsync(cnt, 0, (size_t)NPAD * 4, stream);

    k_prep<<<15384, 256, 0, stream>>>(x, xb, xq, dst, cnt, w1a, w1r, w2r, w2a,
                                      wcat1, wcat2);
    k_scan1<<<NB_SCAN, 256, 0, stream>>>(cnt, bsums);
    k_scan2<<<1, 512, 0, stream>>>(bsums);
    k_scan3<<<NB_SCAN, 256, 0, stream>>>(cnt, bsums, row_start, cursor, invdeg);
    k_fill<<<N_EDGES / 256, 256, 0, stream>>>(src, dst, cursor, csr_src);

    k_gather<<<(N_NODES + 3) / 4, 256, 0, stream>>>(
        xq, row_start, cnt, csr_src, invdeg, meanb);

    dim3 g1(NROWPAD / 128, 2);
    k_gemm<128, 0><<<g1, 256, 0, stream>>>(meanb, xb, wcat1, b1, (void*)hb, nullptr);

    dim3 g2(NROWPAD / 128, 1);
    k_gemm<256, 1><<<g2, 256, 0, stream>>>(hb, hb, wcat2, b2, (void*)zrb, (void*)zaq);

    k_final<<<12500, 256, 0, stream>>>(
        zrb, zaq, row_start, cnt, invdeg, csr_src, out);
}

// Round 9
// 191.810 us; speedup vs baseline: 19.1739x; 1.0548x over previous
//
#include <hip/hip_runtime.h>

#define N_NODES 100000
#define N_EDGES 640000
#define D_IN 128
#define D_HID 256
#define D_OUT 64

#define NPAD 100352                  // N padded to 256 (for scan)
#define NROWPAD 100096               // N padded to 128 (GEMM tiles, no guards)
#define NB_SCAN 391                  // ceil(100000/256)

// ---------------- workspace layout (byte offsets, all 16B-aligned) -------
#define OB_CNT      0u
#define OB_RSTART   401408u
#define OB_CURSOR   802816u
#define OB_BSUMS    1204224u
#define OB_CSRC     1206272u
#define OB_INVDEG   3766272u
#define OB_XB       4167680u                    // bf16 [NROWPAD][128]
#define OB_XQ       29792256u                   // fp8  [NROWPAD][128]
#define OB_MEANB    42604544u                   // bf16 [NROWPAD][128]
#define OB_HB       68229120u                   // bf16 [NROWPAD][256]
#define OB_ZRB      119478272u                  // bf16 [NROWPAD][64] root+bias
#define OB_ZAQ      132290560u                  // fp8  [NROWPAD][64] agg half
#define OB_WCAT1    138696704u                  // bf16 [256][256]
#define OB_WCAT2    138827776u                  // bf16 [128][256]

typedef __attribute__((ext_vector_type(8))) short bf16x8;
typedef __attribute__((ext_vector_type(8))) ushort ushort8;
typedef __attribute__((ext_vector_type(4))) float f32x4;
typedef __attribute__((ext_vector_type(2))) float f32x2;

__device__ __forceinline__ ushort f2bf(float f) {
    uint u = __float_as_uint(f);
    u += 0x7FFFu + ((u >> 16) & 1u);          // round-to-nearest-even
    return (ushort)(u >> 16);
}
__device__ __forceinline__ float bf1(ushort u) { return __uint_as_float((uint)u << 16); }
__device__ __forceinline__ uchar f2q(float v) {   // f32 -> e4m3 (OCP on gfx950)
    return (uchar)(__builtin_amdgcn_cvt_pk_fp8_f32(v, v, 0, false) & 0xFF);
}
__device__ __forceinline__ uint pk8(float4 v) {   // 4 f32 -> 4 fp8
    uint q = (uint)__builtin_amdgcn_cvt_pk_fp8_f32(v.x, v.y, 0, false);
    return (uint)__builtin_amdgcn_cvt_pk_fp8_f32(v.z, v.w, (int)q, true);
}

// ---------------- fused prologue: cast x -> bf16+fp8 | hist | weights ----
// cast: 16 elems/thread (4 independent float4 loads) for BW saturation.

__global__ __launch_bounds__(256) void k_prep(
    const float* __restrict__ x, ushort* __restrict__ xb,
    uchar* __restrict__ xq,
    const int* __restrict__ dst, int* __restrict__ cnt,
    const float* __restrict__ w1a, const float* __restrict__ w1r,
    const float* __restrict__ w2r, const float* __restrict__ w2a,
    ushort* __restrict__ wcat1, ushort* __restrict__ wcat2)
{
    int b = blockIdx.x;
    if (b < 3125) {                   // cast x (12.8M elems, 16/thread)
        size_t i = ((size_t)b * 256 + threadIdx.x) * 16;
        float4 v0 = *(const float4*)(x + i);
        float4 v1 = *(const float4*)(x + i + 4);
        float4 v2 = *(const float4*)(x + i + 8);
        float4 v3 = *(const float4*)(x + i + 12);
        ushort8 o0, o1;
        o0[0]=f2bf(v0.x); o0[1]=f2bf(v0.y); o0[2]=f2bf(v0.z); o0[3]=f2bf(v0.w);
        o0[4]=f2bf(v1.x); o0[5]=f2bf(v1.y); o0[6]=f2bf(v1.z); o0[7]=f2bf(v1.w);
        o1[0]=f2bf(v2.x); o1[1]=f2bf(v2.y); o1[2]=f2bf(v2.z); o1[3]=f2bf(v2.w);
        o1[4]=f2bf(v3.x); o1[5]=f2bf(v3.y); o1[6]=f2bf(v3.z); o1[7]=f2bf(v3.w);
        *(ushort8*)(xb + i) = o0;
        *(ushort8*)(xb + i + 8) = o1;
        uint4 q;
        q.x = pk8(v0); q.y = pk8(v1); q.z = pk8(v2); q.w = pk8(v3);
        *(uint4*)(xq + i) = q;
    } else if (b < 5625) {            // degree histogram
        int e = (b - 3125) * 256 + threadIdx.x;
        atomicAdd(&cnt[dst[e]], 1);
    } else {                          // weight concat + cast (384 blocks)
        int i = (b - 5625) * 256 + threadIdx.x;
        if (i < 65536) {              // wcat1 [256][256] = [w1a | w1r]
            int n = i >> 8, k = i & 255;
            float v = (k < 128) ? w1a[n * 128 + k] : w1r[n * 128 + (k - 128)];
            wcat1[i] = f2bf(v);
        } else {                      // wcat2 [128][256] = [w2r ; w2a]
            int j = i - 65536;
            int n = j >> 8, k = j & 255;
            float v = (n < 64) ? w2r[n * 256 + k] : w2a[(n - 64) * 256 + k];
            wcat2[j] = f2bf(v);
        }
    }
}

// ---------------- CSR build (scan chain, scan2 fused into scan3) ---------

__global__ __launch_bounds__(256) void k_scan1(
    const int* __restrict__ cnt, int* __restrict__ bsums)
{
    __shared__ int s[256];
    int i = blockIdx.x * 256 + threadIdx.x;
    int v = (i < N_NODES) ? cnt[i] : 0;
    s[threadIdx.x] = v;
    __syncthreads();
    for (int o = 128; o > 0; o >>= 1) {
        if (threadIdx.x < o) s[threadIdx.x] += s[threadIdx.x + o];
        __syncthreads();
    }
    if (threadIdx.x == 0) bsums[blockIdx.x] = s[0];
}

__global__ __launch_bounds__(256) void k_scan3(
    const int* __restrict__ cnt, const int* __restrict__ bsums,
    int* __restrict__ row_start, int* __restrict__ cursor,
    float* __restrict__ invdeg)
{
    __shared__ int r[256];
    __shared__ int s[256];
    int bid = blockIdx.x;
    // block offset = sum of bsums[0..bid-1] (redundant per-block reduce)
    int acc = 0;
    int i1 = threadIdx.x, i2 = threadIdx.x + 256;
    if (i1 < bid) acc += bsums[i1];
    if (i2 < bid && i2 < NB_SCAN) acc += bsums[i2];
    r[threadIdx.x] = acc;
    __syncthreads();
    for (int o = 128; o > 0; o >>= 1) {
        if (threadIdx.x < o) r[threadIdx.x] += r[threadIdx.x + o];
        __syncthreads();
    }
    int blockoff = r[0];

    int i = bid * 256 + threadIdx.x;
    int v = (i < N_NODES) ? cnt[i] : 0;
    s[threadIdx.x] = v;
    __syncthreads();
    for (int o = 1; o < 256; o <<= 1) {
        int a = (threadIdx.x >= o) ? s[threadIdx.x - o] : 0;
        __syncthreads();
        s[threadIdx.x] += a;
        __syncthreads();
    }
    if (i < N_NODES) {
        int excl = s[threadIdx.x] - v + blockoff;
        row_start[i] = excl;
        cursor[i] = excl;
        invdeg[i] = 1.0f / fmaxf((float)v, 1.0f);
    }
}

__global__ __launch_bounds__(256) void k_fill(
    const int* __restrict__ src, const int* __restrict__ dst,
    int* __restrict__ cursor, int* __restrict__ csr_src)
{
    int e = blockIdx.x * 256 + threadIdx.x;
    int pos = atomicAdd(&cursor[dst[e]], 1);
    csr_src[pos] = src[e];
}

// ---------------- gather-mean of xq (fp8) rows -----------------------------
// TWO nodes per wave (32 lanes each).  slot g=l&3 (4 neighbors/iter),
// chunk t=l>>2 (16B of the 128B row).  Register-halving butterfly over
// lane bits 0-1 leaves each lane 4 contiguous elems -> ushort4 store.

__global__ __launch_bounds__(256) void k_gather(
    const uchar* __restrict__ xq, const int* __restrict__ row_start,
    const int* __restrict__ cnt, const int* __restrict__ csr_src,
    const float* __restrict__ invdeg, ushort* __restrict__ meanb)
{
    int tid = threadIdx.x;
    int node = blockIdx.x * 8 + (tid >> 5);   // 12500*8 = 100000 exactly
    int l = tid & 31;
    int g = l & 3, t = l >> 2;
    int n = cnt[node];
    const int* cs = csr_src + row_start[node];

    float a[16] = {};
    for (int j = 0; j < n; j += 4) {
        int jj = j + g;
        int ii = (jj < n) ? jj : 0;
        float w = (jj < n) ? 1.0f : 0.0f;
        int s = cs[ii];
        uint4 q = *(const uint4*)(xq + (size_t)s * D_IN + t * 16);
        f32x2 p;
        p = __builtin_amdgcn_cvt_pk_f32_fp8(q.x, false); a[0] += w*p.x; a[1] += w*p.y;
        p = __builtin_amdgcn_cvt_pk_f32_fp8(q.x, true);  a[2] += w*p.x; a[3] += w*p.y;
        p = __builtin_amdgcn_cvt_pk_f32_fp8(q.y, false); a[4] += w*p.x; a[5] += w*p.y;
        p = __builtin_amdgcn_cvt_pk_f32_fp8(q.y, true);  a[6] += w*p.x; a[7] += w*p.y;
        p = __builtin_amdgcn_cvt_pk_f32_fp8(q.z, false); a[8] += w*p.x; a[9] += w*p.y;
        p = __builtin_amdgcn_cvt_pk_f32_fp8(q.z, true);  a[10]+= w*p.x; a[11]+= w*p.y;
        p = __builtin_amdgcn_cvt_pk_f32_fp8(q.w, false); a[12]+= w*p.x; a[13]+= w*p.y;
        p = __builtin_amdgcn_cvt_pk_f32_fp8(q.w, true);  a[14]+= w*p.x; a[15]+= w*p.y;
    }

    // stage A: lane bit0 <-> value-index bit2
    float b[8];
    #pragma unroll
    for (int j = 0; j < 8; ++j) {
        int base = (j & 3) + 8 * (j >> 2);
        float mine = (l & 1) ? a[base + 4] : a[base];
        float send = (l & 1) ? a[base]     : a[base + 4];
        b[j] = mine + __shfl_xor(send, 1);
    }
    // stage B: lane bit1 <-> value-index bit3
    float c[4];
    #pragma unroll
    for (int j = 0; j < 4; ++j) {
        float mine = (l & 2) ? b[j + 4] : b[j];
        float send = (l & 2) ? b[j]     : b[j + 4];
        c[j] = mine + __shfl_xor(send, 2);
    }
    // lane owns elements t*16 + (l&3)*4 + {0..3}
    float id = invdeg[node];
    ushort4 o;
    o.x = f2bf(c[0] * id); o.y = f2bf(c[1] * id);
    o.z = f2bf(c[2] * id); o.w = f2bf(c[3] * id);
    *(ushort4*)(meanb + (size_t)node * D_IN + t * 16 + (l & 3) * 4) = o;
}

// ---------------- MFMA GEMM: OUT[M,*] = [A0|A1] @ Bcat.T ------------------
// 128x128 tile, 4 waves (2x2), BK=64, K=256.  LDS XOR-swizzled (rule #21):
// pre-swizzled global source + linear global_load_lds dest + swizzled read.
// MODE 0: out0 = bf16 [M][256] relu(v + bias)        (layer 1)
// MODE 1: out0 = bf16 [M][64] v+bias (cols 0-63), out1 = fp8 [M][64] (cols 64-127)

template<int AW, int MODE>
__global__ __launch_bounds__(256, 2) void k_gemm(
    const ushort* __restrict__ A0, const ushort* __restrict__ A1,
    const ushort* __restrict__ B,     // [*][256] bf16
    const float* __restrict__ bias,
    void* __restrict__ out0, void* __restrict__ out1)
{
    __shared__ ushort lds[2 * 128 * 64];   // A: [0,16KB), B: [16KB,32KB)

    const int tid = threadIdx.x;
    const int lane = tid & 63;
    const int w = tid >> 6;
    const int wm = w >> 1, wn = w & 1;
    const int row0 = blockIdx.x * 128;
    const int col0 = blockIdx.y * 128;

    f32x4 acc[4][4] = {};   // [mi][ni]

    for (int kt = 0; kt < 4; ++kt) {
        const int k0 = kt * 64;
        const ushort* asrc;
        int kofs;
        if (AW == 256) { asrc = A0; kofs = k0; }
        else { asrc = (k0 < 128) ? A0 : A1; kofs = k0 & 127; }

        // stage A tile [128 rows][64 bf16], 4 issues x 4KB
        #pragma unroll
        for (int i = 0; i < 4; ++i) {
            int elem = i * 256 + tid;         // 16B-chunk index
            int r = elem >> 3;                // row 0..127
            int c8 = (elem & 7) ^ (r & 7);    // swizzled source chunk
            const ushort* g = asrc + (size_t)(row0 + r) * AW + kofs + c8 * 8;
            __builtin_amdgcn_global_load_lds(
                (const __attribute__((address_space(1))) void*)g,
                (__attribute__((address_space(3))) void*)&lds[i * 2048 + w * 512],
                16, 0, 0);
        }
        // stage B tile
        #pragma unroll
        for (int i = 0; i < 4; ++i) {
            int elem = i * 256 + tid;
            int r = elem >> 3;
            int c8 = (elem & 7) ^ (r & 7);
            const ushort* g = B + (size_t)(col0 + r) * 256 + k0 + c8 * 8;
            __builtin_amdgcn_global_load_lds(
                (const __attribute__((address_space(1))) void*)g,
                (__attribute__((address_space(3))) void*)&lds[8192 + i * 2048 + w * 512],
                16, 0, 0);
        }
        asm volatile("s_waitcnt vmcnt(0)" ::: "memory");
        __syncthreads();

        #pragma unroll
        for (int ks = 0; ks < 2; ++ks) {
            bf16x8 af[4], bfr[4];
            #pragma unroll
            for (int mi = 0; mi < 4; ++mi) {
                int r = wm * 64 + mi * 16 + (lane & 15);
                int c8 = ks * 4 + (lane >> 4);
                int byteoff = r * 128 + ((c8 ^ (r & 7)) * 16);
                af[mi] = *(const bf16x8*)((const char*)lds + byteoff);
            }
            #pragma unroll
            for (int ni = 0; ni < 4; ++ni) {
                int r = wn * 64 + ni * 16 + (lane & 15);
                int c8 = ks * 4 + (lane >> 4);
                int byteoff = 16384 + r * 128 + ((c8 ^ (r & 7)) * 16);
                bfr[ni] = *(const bf16x8*)((const char*)lds + byteoff);
            }
            #pragma unroll
            for (int mi = 0; mi < 4; ++mi)
                #pragma unroll
                for (int ni = 0; ni < 4; ++ni)
                    acc[mi][ni] = __builtin_amdgcn_mfma_f32_16x16x32_bf16(
                        af[mi], bfr[ni], acc[mi][ni], 0, 0, 0);
        }
        __syncthreads();
    }

    // epilogue: C/D map col=lane&15, row=(lane>>4)*4+reg
    const int orow_base = row0 + wm * 64;
    const int ocol_base = col0 + wn * 64;
    #pragma unroll
    for (int mi = 0; mi < 4; ++mi) {
        #pragma unroll
        for (int ni = 0; ni < 4; ++ni) {
            int ocol = ocol_base + ni * 16 + (lane & 15);
            #pragma unroll
            for (int r = 0; r < 4; ++r) {
                int orow = orow_base + mi * 16 + (lane >> 4) * 4 + r;
                float v = acc[mi][ni][r];
                if (MODE == 0) {
                    v = fmaxf(v + bias[ocol], 0.0f);
                    ((ushort*)out0)[(size_t)orow * 256 + ocol] = f2bf(v);
                } else {
                    if (ocol < 64)
                        ((ushort*)out0)[(size_t)orow * 64 + ocol] = f2bf(v + bias[ocol]);
                    else
                        ((uchar*)out1)[(size_t)orow * 64 + (ocol - 64)] = f2q(v);
                }
            }
        }
    }
}

// -------- final: gather-mean zaq (fp8) + zrb + log_softmax ---------------
// TWO nodes per wave (32 lanes each).  slot g=l&7 (8 neighbors/iter),
// chunk t=l>>3 (16B of the 64B row).  Butterfly register-halving reduce;
// lane ends with classes t*16+(l&7) and +8.

__global__ __launch_bounds__(256) void k_final(
    const ushort* __restrict__ zrb, const uchar* __restrict__ zaq,
    const int* __restrict__ row_start, const int* __restrict__ cnt,
    const float* __restrict__ invdeg, const int* __restrict__ csr_src,
    float* __restrict__ out)
{
    int tid = threadIdx.x;
    int lane = tid & 63;
    int l = lane & 31;
    int node = blockIdx.x * 8 + (tid >> 5);   // 12500*8 = 100000 exactly
    int g = l & 7, t = l >> 3;
    int n = cnt[node];
    const int* cs = csr_src + row_start[node];

    float a[16] = {};
    for (int j = 0; j < n; j += 8) {
        int jj = j + g;
        int ii = (jj < n) ? jj : 0;
        float w = (jj < n) ? 1.0f : 0.0f;
        int s = cs[ii];
        uint4 q = *(const uint4*)(zaq + (size_t)s * 64 + t * 16);
        f32x2 p;
        p = __builtin_amdgcn_cvt_pk_f32_fp8(q.x, false); a[0] += w*p.x; a[1] += w*p.y;
        p = __builtin_amdgcn_cvt_pk_f32_fp8(q.x, true);  a[2] += w*p.x; a[3] += w*p.y;
        p = __builtin_amdgcn_cvt_pk_f32_fp8(q.y, false); a[4] += w*p.x; a[5] += w*p.y;
        p = __builtin_amdgcn_cvt_pk_f32_fp8(q.y, true);  a[6] += w*p.x; a[7] += w*p.y;
        p = __builtin_amdgcn_cvt_pk_f32_fp8(q.z, false); a[8] += w*p.x; a[9] += w*p.y;
        p = __builtin_amdgcn_cvt_pk_f32_fp8(q.z, true);  a[10]+= w*p.x; a[11]+= w*p.y;
        p = __builtin_amdgcn_cvt_pk_f32_fp8(q.w, false); a[12]+= w*p.x; a[13]+= w*p.y;
        p = __builtin_amdgcn_cvt_pk_f32_fp8(q.w, true);  a[14]+= w*p.x; a[15]+= w*p.y;
    }

    // butterfly reduce over lane bits 0..2, halving registers each stage
    float b[8];
    #pragma unroll
    for (int j = 0; j < 8; ++j) {
        float mine = (l & 1) ? a[2*j+1] : a[2*j];
        float send = (l & 1) ? a[2*j]   : a[2*j+1];
        b[j] = mine + __shfl_xor(send, 1);
    }
    float c[4];
    #pragma unroll
    for (int j = 0; j < 4; ++j) {
        float mine = (l & 2) ? b[2*j+1] : b[2*j];
        float send = (l & 2) ? b[2*j]   : b[2*j+1];
        c[j] = mine + __shfl_xor(send, 2);
    }
    float m0 = (l & 4) ? c[1] : c[0];
    float s0 = (l & 4) ? c[0] : c[1];
    float e0 = m0 + __shfl_xor(s0, 4);
    float m1 = (l & 4) ? c[3] : c[2];
    float s1 = (l & 4) ? c[2] : c[3];
    float e1 = m1 + __shfl_xor(s1, 4);

    int c0 = t * 16 + (l & 7);
    float id = invdeg[node];
    float v0 = e0 * id + bf1(zrb[(size_t)node * 64 + c0]);
    float v1 = e1 * id + bf1(zrb[(size_t)node * 64 + c0 + 8]);

    float m = fmaxf(v0, v1);
    #pragma unroll
    for (int o = 1; o < 32; o <<= 1) m = fmaxf(m, __shfl_xor(m, o));
    float ssum = __expf(v0 - m) + __expf(v1 - m);
    #pragma unroll
    for (int o = 1; o < 32; o <<= 1) ssum += __shfl_xor(ssum, o);
    float lse = m + __logf(ssum);

    out[(size_t)node * 64 + c0]     = v0 - lse;
    out[(size_t)node * 64 + c0 + 8] = v1 - lse;
}

// ---------------- launch ----------------

extern "C" void kernel_launch(void* const* d_in, const int* in_sizes, int n_in,
                              void* d_out, int out_size, void* d_ws, size_t ws_size,
                              hipStream_t stream)
{
    const float* x   = (const float*)d_in[0];
    const int*   ei  = (const int*)d_in[1];
    const float* w1a = (const float*)d_in[2];
    const float* b1  = (const float*)d_in[3];
    const float* w1r = (const float*)d_in[4];
    const float* w2a = (const float*)d_in[5];
    const float* b2  = (const float*)d_in[6];
    const float* w2r = (const float*)d_in[7];
    float* out = (float*)d_out;

    char* ws = (char*)d_ws;
    const int* src = ei;
    const int* dst = ei + N_EDGES;

    int*    cnt       = (int*)(ws + OB_CNT);
    int*    row_start = (int*)(ws + OB_RSTART);
    int*    cursor    = (int*)(ws + OB_CURSOR);
    int*    bsums     = (int*)(ws + OB_BSUMS);
    int*    csr_src   = (int*)(ws + OB_CSRC);
    float*  invdeg    = (float*)(ws + OB_INVDEG);
    ushort* xb        = (ushort*)(ws + OB_XB);
    uchar*  xq        = (uchar*)(ws + OB_XQ);
    ushort* meanb     = (ushort*)(ws + OB_MEANB);
    ushort* hb        = (ushort*)(ws + OB_HB);
    ushort* zrb       = (ushort*)(ws + OB_ZRB);
    uchar*  zaq       = (uchar*)(ws + OB_ZAQ);
    ushort* wcat1     = (ushort*)(ws + OB_WCAT1);
    ushort* wcat2     = (ushort*)(ws + OB_WCAT2);

    hipMemsetAsync(cnt, 0, (size_t)NPAD * 4, stream);

    k_prep<<<6009, 256, 0, stream>>>(x, xb, xq, dst, cnt, w1a, w1r, w2r, w2a,
                                     wcat1, wcat2);
    k_scan1<<<NB_SCAN, 256, 0, stream>>>(cnt, bsums);
    k_scan3<<<NB_SCAN, 256, 0, stream>>>(cnt, bsums, row_start, cursor, invdeg);
    k_fill<<<N_EDGES / 256, 256, 0, stream>>>(src, dst, cursor, csr_src);

    k_gather<<<12500, 256, 0, stream>>>(
        xq, row_start, cnt, csr_src, invdeg, meanb);

    dim3 g1(NROWPAD / 128, 2);
    k_gemm<128, 0><<<g1, 256, 0, stream>>>(meanb, xb, wcat1, b1, (void*)hb, nullptr);

    dim3 g2(NROWPAD / 128, 1);
    k_gemm<256, 1><<<g2, 256, 0, stream>>>(hb, hb, wcat2, b2, (void*)zrb, (void*)zaq);

    k_final<<<12500, 256, 0, stream>>>(
        zrb, zaq, row_start, cnt, invdeg, csr_src, out);
}

// Round 10
// 191.184 us; speedup vs baseline: 19.2367x; 1.0033x over previous
//
#include <hip/hip_runtime.h>

#define N_NODES 100000
#define N_EDGES 640000
#define D_IN 128
#define D_HID 256
#define D_OUT 64

#define NPAD 100352                  // N padded to 256 (for scan)
#define NROWPAD 100096               // N padded to 128 (GEMM tiles, no guards)
#define NB_SCAN 391                  // ceil(100000/256)

// ---------------- workspace layout (byte offsets, all 16B-aligned) -------
#define OB_CNT      0u
#define OB_RSTART   401408u
#define OB_CURSOR   802816u
#define OB_BSUMS    1204224u
#define OB_CSRC     1206272u
#define OB_INVDEG   3766272u
#define OB_XB       4167680u                    // bf16 [NROWPAD][128]
#define OB_XQ       29792256u                   // fp8  [NROWPAD][128]
#define OB_MEANB    42604544u                   // bf16 [NROWPAD][128]
#define OB_HB       68229120u                   // bf16 [NROWPAD][256]
#define OB_ZRB      119478272u                  // bf16 [NROWPAD][64] root+bias
#define OB_ZAQ      132290560u                  // fp8  [NROWPAD][64] agg half
#define OB_WCAT1    138696704u                  // bf16 [256][256]
#define OB_WCAT2    138827776u                  // bf16 [128][256]

typedef __attribute__((ext_vector_type(8))) short bf16x8;
typedef __attribute__((ext_vector_type(8))) ushort ushort8;
typedef __attribute__((ext_vector_type(4))) float f32x4;
typedef __attribute__((ext_vector_type(2))) float f32x2;

__device__ __forceinline__ ushort f2bf(float f) {
    uint u = __float_as_uint(f);
    u += 0x7FFFu + ((u >> 16) & 1u);          // round-to-nearest-even
    return (ushort)(u >> 16);
}
__device__ __forceinline__ float bf1(ushort u) { return __uint_as_float((uint)u << 16); }
__device__ __forceinline__ uchar f2q(float v) {   // f32 -> e4m3 (OCP on gfx950)
    return (uchar)(__builtin_amdgcn_cvt_pk_fp8_f32(v, v, 0, false) & 0xFF);
}
__device__ __forceinline__ uint pk8(float4 v) {   // 4 f32 -> 4 fp8
    uint q = (uint)__builtin_amdgcn_cvt_pk_fp8_f32(v.x, v.y, 0, false);
    return (uint)__builtin_amdgcn_cvt_pk_fp8_f32(v.z, v.w, (int)q, true);
}

// ---------------- streaming prologue: cast x -> bf16+fp8 | weights -------

__global__ __launch_bounds__(256) void k_cast(
    const float* __restrict__ x, ushort* __restrict__ xb,
    uchar* __restrict__ xq,
    const float* __restrict__ w1a, const float* __restrict__ w1r,
    const float* __restrict__ w2r, const float* __restrict__ w2a,
    ushort* __restrict__ wcat1, ushort* __restrict__ wcat2)
{
    int b = blockIdx.x;
    if (b < 3125) {                   // cast x (12.8M elems, 16/thread)
        size_t i = ((size_t)b * 256 + threadIdx.x) * 16;
        float4 v0 = *(const float4*)(x + i);
        float4 v1 = *(const float4*)(x + i + 4);
        float4 v2 = *(const float4*)(x + i + 8);
        float4 v3 = *(const float4*)(x + i + 12);
        ushort8 o0, o1;
        o0[0]=f2bf(v0.x); o0[1]=f2bf(v0.y); o0[2]=f2bf(v0.z); o0[3]=f2bf(v0.w);
        o0[4]=f2bf(v1.x); o0[5]=f2bf(v1.y); o0[6]=f2bf(v1.z); o0[7]=f2bf(v1.w);
        o1[0]=f2bf(v2.x); o1[1]=f2bf(v2.y); o1[2]=f2bf(v2.z); o1[3]=f2bf(v2.w);
        o1[4]=f2bf(v3.x); o1[5]=f2bf(v3.y); o1[6]=f2bf(v3.z); o1[7]=f2bf(v3.w);
        *(ushort8*)(xb + i) = o0;
        *(ushort8*)(xb + i + 8) = o1;
        uint4 q;
        q.x = pk8(v0); q.y = pk8(v1); q.z = pk8(v2); q.w = pk8(v3);
        *(uint4*)(xq + i) = q;
    } else {                          // weight concat + cast (384 blocks)
        int i = (b - 3125) * 256 + threadIdx.x;
        if (i < 65536) {              // wcat1 [256][256] = [w1a | w1r]
            int n = i >> 8, k = i & 255;
            float v = (k < 128) ? w1a[n * 128 + k] : w1r[n * 128 + (k - 128)];
            wcat1[i] = f2bf(v);
        } else {                      // wcat2 [128][256] = [w2r ; w2a]
            int j = i - 65536;
            int n = j >> 8, k = j & 255;
            float v = (n < 64) ? w2r[n * 256 + k] : w2a[(n - 64) * 256 + k];
            wcat2[j] = f2bf(v);
        }
    }
}

// ---------------- degree histogram: 4 edges/thread, int4 index reads -----

__global__ __launch_bounds__(256) void k_hist(
    const int* __restrict__ dst, int* __restrict__ cnt)
{
    int e = (blockIdx.x * 256 + threadIdx.x) * 4;
    int4 d = *(const int4*)(dst + e);
    atomicAdd(&cnt[d.x], 1);
    atomicAdd(&cnt[d.y], 1);
    atomicAdd(&cnt[d.z], 1);
    atomicAdd(&cnt[d.w], 1);
}

// ---------------- CSR build (scan chain, scan2 fused into scan3) ---------

__global__ __launch_bounds__(256) void k_scan1(
    const int* __restrict__ cnt, int* __restrict__ bsums)
{
    __shared__ int s[256];
    int i = blockIdx.x * 256 + threadIdx.x;
    int v = (i < N_NODES) ? cnt[i] : 0;
    s[threadIdx.x] = v;
    __syncthreads();
    for (int o = 128; o > 0; o >>= 1) {
        if (threadIdx.x < o) s[threadIdx.x] += s[threadIdx.x + o];
        __syncthreads();
    }
    if (threadIdx.x == 0) bsums[blockIdx.x] = s[0];
}

__global__ __launch_bounds__(256) void k_scan3(
    const int* __restrict__ cnt, const int* __restrict__ bsums,
    int* __restrict__ row_start, int* __restrict__ cursor,
    float* __restrict__ invdeg)
{
    __shared__ int r[256];
    __shared__ int s[256];
    int bid = blockIdx.x;
    // block offset = sum of bsums[0..bid-1] (redundant per-block reduce)
    int acc = 0;
    int i1 = threadIdx.x, i2 = threadIdx.x + 256;
    if (i1 < bid) acc += bsums[i1];
    if (i2 < bid && i2 < NB_SCAN) acc += bsums[i2];
    r[threadIdx.x] = acc;
    __syncthreads();
    for (int o = 128; o > 0; o >>= 1) {
        if (threadIdx.x < o) r[threadIdx.x] += r[threadIdx.x + o];
        __syncthreads();
    }
    int blockoff = r[0];

    int i = bid * 256 + threadIdx.x;
    int v = (i < N_NODES) ? cnt[i] : 0;
    s[threadIdx.x] = v;
    __syncthreads();
    for (int o = 1; o < 256; o <<= 1) {
        int a = (threadIdx.x >= o) ? s[threadIdx.x - o] : 0;
        __syncthreads();
        s[threadIdx.x] += a;
        __syncthreads();
    }
    if (i < N_NODES) {
        int excl = s[threadIdx.x] - v + blockoff;
        row_start[i] = excl;
        cursor[i] = excl;
        invdeg[i] = 1.0f / fmaxf((float)v, 1.0f);
    }
}

// ---------------- fill: 4 edges/thread, 4 independent atomic chains ------

__global__ __launch_bounds__(256) void k_fill(
    const int* __restrict__ src, const int* __restrict__ dst,
    int* __restrict__ cursor, int* __restrict__ csr_src)
{
    int e = (blockIdx.x * 256 + threadIdx.x) * 4;
    int4 d = *(const int4*)(dst + e);
    int4 sv = *(const int4*)(src + e);
    int p0 = atomicAdd(&cursor[d.x], 1);
    int p1 = atomicAdd(&cursor[d.y], 1);
    int p2 = atomicAdd(&cursor[d.z], 1);
    int p3 = atomicAdd(&cursor[d.w], 1);
    csr_src[p0] = sv.x;
    csr_src[p1] = sv.y;
    csr_src[p2] = sv.z;
    csr_src[p3] = sv.w;
}

// ---------------- gather-mean of xq (fp8) rows -----------------------------
// TWO nodes per wave (32 lanes each).  slot g=l&3 (4 neighbors/iter),
// chunk t=l>>2 (16B of the 128B row).  Register-halving butterfly over
// lane bits 0-1 leaves each lane 4 contiguous elems -> ushort4 store.

__global__ __launch_bounds__(256) void k_gather(
    const uchar* __restrict__ xq, const int* __restrict__ row_start,
    const int* __restrict__ cnt, const int* __restrict__ csr_src,
    const float* __restrict__ invdeg, ushort* __restrict__ meanb)
{
    int tid = threadIdx.x;
    int node = blockIdx.x * 8 + (tid >> 5);   // 12500*8 = 100000 exactly
    int l = tid & 31;
    int g = l & 3, t = l >> 2;
    int n = cnt[node];
    const int* cs = csr_src + row_start[node];

    float a[16] = {};
    for (int j = 0; j < n; j += 4) {
        int jj = j + g;
        int ii = (jj < n) ? jj : 0;
        float w = (jj < n) ? 1.0f : 0.0f;
        int s = cs[ii];
        uint4 q = *(const uint4*)(xq + (size_t)s * D_IN + t * 16);
        f32x2 p;
        p = __builtin_amdgcn_cvt_pk_f32_fp8(q.x, false); a[0] += w*p.x; a[1] += w*p.y;
        p = __builtin_amdgcn_cvt_pk_f32_fp8(q.x, true);  a[2] += w*p.x; a[3] += w*p.y;
        p = __builtin_amdgcn_cvt_pk_f32_fp8(q.y, false); a[4] += w*p.x; a[5] += w*p.y;
        p = __builtin_amdgcn_cvt_pk_f32_fp8(q.y, true);  a[6] += w*p.x; a[7] += w*p.y;
        p = __builtin_amdgcn_cvt_pk_f32_fp8(q.z, false); a[8] += w*p.x; a[9] += w*p.y;
        p = __builtin_amdgcn_cvt_pk_f32_fp8(q.z, true);  a[10]+= w*p.x; a[11]+= w*p.y;
        p = __builtin_amdgcn_cvt_pk_f32_fp8(q.w, false); a[12]+= w*p.x; a[13]+= w*p.y;
        p = __builtin_amdgcn_cvt_pk_f32_fp8(q.w, true);  a[14]+= w*p.x; a[15]+= w*p.y;
    }

    // stage A: lane bit0 <-> value-index bit2
    float b[8];
    #pragma unroll
    for (int j = 0; j < 8; ++j) {
        int base = (j & 3) + 8 * (j >> 2);
        float mine = (l & 1) ? a[base + 4] : a[base];
        float send = (l & 1) ? a[base]     : a[base + 4];
        b[j] = mine + __shfl_xor(send, 1);
    }
    // stage B: lane bit1 <-> value-index bit3
    float c[4];
    #pragma unroll
    for (int j = 0; j < 4; ++j) {
        float mine = (l & 2) ? b[j + 4] : b[j];
        float send = (l & 2) ? b[j]     : b[j + 4];
        c[j] = mine + __shfl_xor(send, 2);
    }
    // lane owns elements t*16 + (l&3)*4 + {0..3}
    float id = invdeg[node];
    ushort4 o;
    o.x = f2bf(c[0] * id); o.y = f2bf(c[1] * id);
    o.z = f2bf(c[2] * id); o.w = f2bf(c[3] * id);
    *(ushort4*)(meanb + (size_t)node * D_IN + t * 16 + (l & 3) * 4) = o;
}

// ---------------- MFMA GEMM: OUT[M,*] = [A0|A1] @ Bcat.T ------------------
// 128x128 tile, 4 waves (2x2), BK=64, K=256.  LDS XOR-swizzled (rule #21):
// pre-swizzled global source + linear global_load_lds dest + swizzled read.
// MODE 0: out0 = bf16 [M][256] relu(v + bias)        (layer 1)
// MODE 1: out0 = bf16 [M][64] v+bias (cols 0-63), out1 = fp8 [M][64] (cols 64-127)

template<int AW, int MODE>
__global__ __launch_bounds__(256, 2) void k_gemm(
    const ushort* __restrict__ A0, const ushort* __restrict__ A1,
    const ushort* __restrict__ B,     // [*][256] bf16
    const float* __restrict__ bias,
    void* __restrict__ out0, void* __restrict__ out1)
{
    __shared__ ushort lds[2 * 128 * 64];   // A: [0,16KB), B: [16KB,32KB)

    const int tid = threadIdx.x;
    const int lane = tid & 63;
    const int w = tid >> 6;
    const int wm = w >> 1, wn = w & 1;
    const int row0 = blockIdx.x * 128;
    const int col0 = blockIdx.y * 128;

    f32x4 acc[4][4] = {};   // [mi][ni]

    for (int kt = 0; kt < 4; ++kt) {
        const int k0 = kt * 64;
        const ushort* asrc;
        int kofs;
        if (AW == 256) { asrc = A0; kofs = k0; }
        else { asrc = (k0 < 128) ? A0 : A1; kofs = k0 & 127; }

        // stage A tile [128 rows][64 bf16], 4 issues x 4KB
        #pragma unroll
        for (int i = 0; i < 4; ++i) {
            int elem = i * 256 + tid;         // 16B-chunk index
            int r = elem >> 3;                // row 0..127
            int c8 = (elem & 7) ^ (r & 7);    // swizzled source chunk
            const ushort* g = asrc + (size_t)(row0 + r) * AW + kofs + c8 * 8;
            __builtin_amdgcn_global_load_lds(
                (const __attribute__((address_space(1))) void*)g,
                (__attribute__((address_space(3))) void*)&lds[i * 2048 + w * 512],
                16, 0, 0);
        }
        // stage B tile
        #pragma unroll
        for (int i = 0; i < 4; ++i) {
            int elem = i * 256 + tid;
            int r = elem >> 3;
            int c8 = (elem & 7) ^ (r & 7);
            const ushort* g = B + (size_t)(col0 + r) * 256 + k0 + c8 * 8;
            __builtin_amdgcn_global_load_lds(
                (const __attribute__((address_space(1))) void*)g,
                (__attribute__((address_space(3))) void*)&lds[8192 + i * 2048 + w * 512],
                16, 0, 0);
        }
        asm volatile("s_waitcnt vmcnt(0)" ::: "memory");
        __syncthreads();

        #pragma unroll
        for (int ks = 0; ks < 2; ++ks) {
            bf16x8 af[4], bfr[4];
            #pragma unroll
            for (int mi = 0; mi < 4; ++mi) {
                int r = wm * 64 + mi * 16 + (lane & 15);
                int c8 = ks * 4 + (lane >> 4);
                int byteoff = r * 128 + ((c8 ^ (r & 7)) * 16);
                af[mi] = *(const bf16x8*)((const char*)lds + byteoff);
            }
            #pragma unroll
            for (int ni = 0; ni < 4; ++ni) {
                int r = wn * 64 + ni * 16 + (lane & 15);
                int c8 = ks * 4 + (lane >> 4);
                int byteoff = 16384 + r * 128 + ((c8 ^ (r & 7)) * 16);
                bfr[ni] = *(const bf16x8*)((const char*)lds + byteoff);
            }
            #pragma unroll
            for (int mi = 0; mi < 4; ++mi)
                #pragma unroll
                for (int ni = 0; ni < 4; ++ni)
                    acc[mi][ni] = __builtin_amdgcn_mfma_f32_16x16x32_bf16(
                        af[mi], bfr[ni], acc[mi][ni], 0, 0, 0);
        }
        __syncthreads();
    }

    // epilogue: C/D map col=lane&15, row=(lane>>4)*4+reg
    const int orow_base = row0 + wm * 64;
    const int ocol_base = col0 + wn * 64;
    #pragma unroll
    for (int mi = 0; mi < 4; ++mi) {
        #pragma unroll
        for (int ni = 0; ni < 4; ++ni) {
            int ocol = ocol_base + ni * 16 + (lane & 15);
            #pragma unroll
            for (int r = 0; r < 4; ++r) {
                int orow = orow_base + mi * 16 + (lane >> 4) * 4 + r;
                float v = acc[mi][ni][r];
                if (MODE == 0) {
                    v = fmaxf(v + bias[ocol], 0.0f);
                    ((ushort*)out0)[(size_t)orow * 256 + ocol] = f2bf(v);
                } else {
                    if (ocol < 64)
                        ((ushort*)out0)[(size_t)orow * 64 + ocol] = f2bf(v + bias[ocol]);
                    else
                        ((uchar*)out1)[(size_t)orow * 64 + (ocol - 64)] = f2q(v);
                }
            }
        }
    }
}

// -------- final: gather-mean zaq (fp8) + zrb + log_softmax ---------------
// TWO nodes per wave (32 lanes each).  slot g=l&7 (8 neighbors/iter),
// chunk t=l>>3 (16B of the 64B row).  Butterfly register-halving reduce;
// lane ends with classes t*16+(l&7) and +8.

__global__ __launch_bounds__(256) void k_final(
    const ushort* __restrict__ zrb, const uchar* __restrict__ zaq,
    const int* __restrict__ row_start, const int* __restrict__ cnt,
    const float* __restrict__ invdeg, const int* __restrict__ csr_src,
    float* __restrict__ out)
{
    int tid = threadIdx.x;
    int lane = tid & 63;
    int l = lane & 31;
    int node = blockIdx.x * 8 + (tid >> 5);   // 12500*8 = 100000 exactly
    int g = l & 7, t = l >> 3;
    int n = cnt[node];
    const int* cs = csr_src + row_start[node];

    float a[16] = {};
    for (int j = 0; j < n; j += 8) {
        int jj = j + g;
        int ii = (jj < n) ? jj : 0;
        float w = (jj < n) ? 1.0f : 0.0f;
        int s = cs[ii];
        uint4 q = *(const uint4*)(zaq + (size_t)s * 64 + t * 16);
        f32x2 p;
        p = __builtin_amdgcn_cvt_pk_f32_fp8(q.x, false); a[0] += w*p.x; a[1] += w*p.y;
        p = __builtin_amdgcn_cvt_pk_f32_fp8(q.x, true);  a[2] += w*p.x; a[3] += w*p.y;
        p = __builtin_amdgcn_cvt_pk_f32_fp8(q.y, false); a[4] += w*p.x; a[5] += w*p.y;
        p = __builtin_amdgcn_cvt_pk_f32_fp8(q.y, true);  a[6] += w*p.x; a[7] += w*p.y;
        p = __builtin_amdgcn_cvt_pk_f32_fp8(q.z, false); a[8] += w*p.x; a[9] += w*p.y;
        p = __builtin_amdgcn_cvt_pk_f32_fp8(q.z, true);  a[10]+= w*p.x; a[11]+= w*p.y;
        p = __builtin_amdgcn_cvt_pk_f32_fp8(q.w, false); a[12]+= w*p.x; a[13]+= w*p.y;
        p = __builtin_amdgcn_cvt_pk_f32_fp8(q.w, true);  a[14]+= w*p.x; a[15]+= w*p.y;
    }

    // butterfly reduce over lane bits 0..2, halving registers each stage
    float b[8];
    #pragma unroll
    for (int j = 0; j < 8; ++j) {
        float mine = (l & 1) ? a[2*j+1] : a[2*j];
        float send = (l & 1) ? a[2*j]   : a[2*j+1];
        b[j] = mine + __shfl_xor(send, 1);
    }
    float c[4];
    #pragma unroll
    for (int j = 0; j < 4; ++j) {
        float mine = (l & 2) ? b[2*j+1] : b[2*j];
        float send = (l & 2) ? b[2*j]   : b[2*j+1];
        c[j] = mine + __shfl_xor(send, 2);
    }
    float m0 = (l & 4) ? c[1] : c[0];
    float s0 = (l & 4) ? c[0] : c[1];
    float e0 = m0 + __shfl_xor(s0, 4);
    float m1 = (l & 4) ? c[3] : c[2];
    float s1 = (l & 4) ? c[2] : c[3];
    float e1 = m1 + __shfl_xor(s1, 4);

    int c0 = t * 16 + (l & 7);
    float id = invdeg[node];
    float v0 = e0 * id + bf1(zrb[(size_t)node * 64 + c0]);
    float v1 = e1 * id + bf1(zrb[(size_t)node * 64 + c0 + 8]);

    float m = fmaxf(v0, v1);
    #pragma unroll
    for (int o = 1; o < 32; o <<= 1) m = fmaxf(m, __shfl_xor(m, o));
    float ssum = __expf(v0 - m) + __expf(v1 - m);
    #pragma unroll
    for (int o = 1; o < 32; o <<= 1) ssum += __shfl_xor(ssum, o);
    float lse = m + __logf(ssum);

    out[(size_t)node * 64 + c0]     = v0 - lse;
    out[(size_t)node * 64 + c0 + 8] = v1 - lse;
}

// ---------------- launch ----------------

extern "C" void kernel_launch(void* const* d_in, const int* in_sizes, int n_in,
                              void* d_out, int out_size, void* d_ws, size_t ws_size,
                              hipStream_t stream)
{
    const float* x   = (const float*)d_in[0];
    const int*   ei  = (const int*)d_in[1];
    const float* w1a = (const float*)d_in[2];
    const float* b1  = (const float*)d_in[3];
    const float* w1r = (const float*)d_in[4];
    const float* w2a = (const float*)d_in[5];
    const float* b2  = (const float*)d_in[6];
    const float* w2r = (const float*)d_in[7];
    float* out = (float*)d_out;

    char* ws = (char*)d_ws;
    const int* src = ei;
    const int* dst = ei + N_EDGES;

    int*    cnt       = (int*)(ws + OB_CNT);
    int*    row_start = (int*)(ws + OB_RSTART);
    int*    cursor    = (int*)(ws + OB_CURSOR);
    int*    bsums     = (int*)(ws + OB_BSUMS);
    int*    csr_src   = (int*)(ws + OB_CSRC);
    float*  invdeg    = (float*)(ws + OB_INVDEG);
    ushort* xb        = (ushort*)(ws + OB_XB);
    uchar*  xq        = (uchar*)(ws + OB_XQ);
    ushort* meanb     = (ushort*)(ws + OB_MEANB);
    ushort* hb        = (ushort*)(ws + OB_HB);
    ushort* zrb       = (ushort*)(ws + OB_ZRB);
    uchar*  zaq       = (uchar*)(ws + OB_ZAQ);
    ushort* wcat1     = (ushort*)(ws + OB_WCAT1);
    ushort* wcat2     = (ushort*)(ws + OB_WCAT2);

    hipMemsetAsync(cnt, 0, (size_t)NPAD * 4, stream);

    k_hist<<<625, 256, 0, stream>>>(dst, cnt);
    k_cast<<<3509, 256, 0, stream>>>(x, xb, xq, w1a, w1r, w2r, w2a,
                                     wcat1, wcat2);
    k_scan1<<<NB_SCAN, 256, 0, stream>>>(cnt, bsums);
    k_scan3<<<NB_SCAN, 256, 0, stream>>>(cnt, bsums, row_start, cursor, invdeg);
    k_fill<<<625, 256, 0, stream>>>(src, dst, cursor, csr_src);

    k_gather<<<12500, 256, 0, stream>>>(
        xq, row_start, cnt, csr_src, invdeg, meanb);

    dim3 g1(NROWPAD / 128, 2);
    k_gemm<128, 0><<<g1, 256, 0, stream>>>(meanb, xb, wcat1, b1, (void*)hb, nullptr);

    dim3 g2(NROWPAD / 128, 1);
    k_gemm<256, 1><<<g2, 256, 0, stream>>>(hb, hb, wcat2, b2, (void*)zrb, (void*)zaq);

    k_final<<<12500, 256, 0, stream>>>(
        zrb, zaq, row_start, cnt, invdeg, csr_src, out);
}